// Round 4
// baseline (1524.993 us; speedup 1.0000x reference)
//
#include <hip/hip_runtime.h>
#include <math.h>

// CMCD sampler: persistent cooperative kernel, 256 blocks x 256 threads
// (1 block/CU — full machine). Phase-parallel: every 512x512 GEMM is split
// as 32 row-groups x 8 col-groups; h lives in global (L2). 6 grid syncs per
// step, 50 total. Median: coarse 512-bin hist (LDS pre-agg, x4-replicated
// global) -> fine 512-bin window hist built in phase 2, selected in update.

typedef __attribute__((ext_vector_type(8))) short short8;
typedef __attribute__((ext_vector_type(4))) float floatx4;
typedef unsigned int u32;
typedef unsigned short u16;

// ---- workspace byte offsets (~4.23 MB) ----
#define WS_BAR     0u         // u32 barrier counter (memset 0 each launch)
#define WS_BETAS   64u        // f32[16]
#define WS_COARSE  128u       // u32[2 parity][4 rep][512]
#define WS_FINE    16512u     // u32[2 parity][4 rep][512]
#define WS_TEP     32896u     // f32[4 kq][8 i][512] te partials
#define WS_G1P     98432u     // f32[8 slice][8 i][512] t-MLP pre-act partials
#define WS_XBF     229504u    // u16[512*64]  x bf16 row-major
#define WS_XBFT0   295040u    // u16[64*512]  x^T bf16 parity 0
#define WS_XBFT1   360576u    // u16[64*512]  x^T bf16 parity 1
#define WS_INWT    426112u    // u16[512*64]  in_W^T
#define WS_OUTWT   491648u    // u16[64*512]  out_W^T
#define WS_HWT     557184u    // u16[3*512*512] h_W^T
#define WS_D2      2130048u   // f32[512*512]
#define WS_H0      3178624u   // u16[512*512] h ping
#define WS_H1      3702912u   // u16[512*512] h pong

__device__ __forceinline__ u16 f2bf(float f) {
  u32 u = __float_as_uint(f);
  u32 r = u + 0x7FFFu + ((u >> 16) & 1u);
  return (u16)(r >> 16);
}
__device__ __forceinline__ float bf2f(u16 v) {
  return __uint_as_float(((u32)v) << 16);
}

// tanh-approx gelu (jax.nn.gelu default approximate=True)
__device__ __forceinline__ float gelu_f(float x) {
  float y = 0.7978845608028654f * (x + 0.044715f * x * x * x);
  float ay = fabsf(y);
  float e = __expf(-2.0f * ay);
  float t = (1.0f - e) / (1.0f + e);
  t = (y < 0.0f) ? -t : t;
  return 0.5f * x * (1.0f + t);
}

__device__ __forceinline__ void gsync(u32* bar, u32 target) {
  __syncthreads();
  if (threadIdx.x == 0) {
    __threadfence();
    __hip_atomic_fetch_add(bar, 1u, __ATOMIC_RELEASE, __HIP_MEMORY_SCOPE_AGENT);
    while (__hip_atomic_load(bar, __ATOMIC_ACQUIRE, __HIP_MEMORY_SCOPE_AGENT) < target) {
      __builtin_amdgcn_s_sleep(2);
    }
  }
  __syncthreads();
}

#define MFMA(a, b, c) __builtin_amdgcn_mfma_f32_16x16x32_bf16((a), (b), (c), 0, 0, 0)

__global__ __launch_bounds__(256) void mega(
    const float* __restrict__ particles, const float* __restrict__ noises,
    const float* __restrict__ grid_t, const float* __restrict__ eps,
    const float* __restrict__ mu, const float* __restrict__ phase,
    const float* __restrict__ in_W, const float* __restrict__ in_b,
    const float* __restrict__ t_W1, const float* __restrict__ t_b1,
    const float* __restrict__ t_W2, const float* __restrict__ t_b2,
    const float* __restrict__ h_W, const float* __restrict__ h_b,
    const float* __restrict__ out_W, const float* __restrict__ out_b,
    float* __restrict__ traj, char* __restrict__ ws)
{
  __shared__ u32 su[512];
  __shared__ float sf[2656];
  __shared__ float medf[4];

  u32* bar = (u32*)(ws + WS_BAR);
  float* BET = (float*)(ws + WS_BETAS);
  float* TEP = (float*)(ws + WS_TEP);
  float* G1P = (float*)(ws + WS_G1P);
  u16* xbf = (u16*)(ws + WS_XBF);
  u16* inWT = (u16*)(ws + WS_INWT);
  u16* outWT = (u16*)(ws + WS_OUTWT);
  u16* hWT = (u16*)(ws + WS_HWT);
  float* d2g = (float*)(ws + WS_D2);
  u16* h0g = (u16*)(ws + WS_H0);
  u16* h1g = (u16*)(ws + WS_H1);

  const int b = blockIdx.x;
  const int tid = threadIdx.x;
  const int wv = tid >> 6, lane = tid & 63;
  const int m = lane & 15, q = lane >> 4;
  u32 rnd = 0;

  // ================= P0: prep jobs (913 jobs over 256 blocks) ================
  for (int j = b; j < 913; j += 256) {
    if (j < 64) {                      // t-MLP pre-act partial, K-chain 128
      int slice = j >> 3, ii = j & 7;
      float* temb = sf;
      if (tid < 128) {
        int kglob = slice * 128 + tid;
        int kc = kglob & 511;
        float cf = 0.1f + (float)kc * (99.9f / 511.0f);
        float e = cf * (float)ii + phase[kc];
        temb[tid] = (kglob < 512) ? sinf(e) : cosf(e);
      }
      __syncthreads();
      for (int h = 0; h < 2; h++) {
        int c = h * 256 + tid;
        float acc = (slice == 0) ? t_b1[c] : 0.0f;
        const float* wp = t_W1 + (u32)(slice * 128) * 512u + c;
#pragma unroll 8
        for (int kk = 0; kk < 128; kk++) acc = fmaf(temb[kk], wp[kk * 512], acc);
        G1P[(slice * 8 + ii) * 512 + c] = acc;
      }
    } else if (j < 896) {              // LDS-tiled weight transposes -> bf16
      float* tile = sf;                // [32][33]
      int tx = tid & 31, ty0 = tid >> 5;
      const float* src; u16* dst; int sstr, dstr;
      if (j < 832) {
        int ti = j - 64; int l = ti >> 8, rem = ti & 255, kt = rem >> 4, ct = rem & 15;
        src = h_W + l * 262144 + kt * 32 * 512 + ct * 32; sstr = 512;
        dst = hWT + l * 262144 + ct * 32 * 512 + kt * 32; dstr = 512;
      } else if (j < 864) {
        int ti = j - 832; int kt = ti >> 4, ct = ti & 15;
        src = in_W + kt * 32 * 512 + ct * 32; sstr = 512;
        dst = inWT + ct * 32 * 64 + kt * 32; dstr = 64;
      } else {
        int ti = j - 864; int ct = ti >> 4, kt = ti & 15;
        src = out_W + kt * 32 * 64 + ct * 32; sstr = 64;
        dst = outWT + ct * 32 * 512 + kt * 32; dstr = 512;
      }
#pragma unroll
      for (int r = 0; r < 4; r++) { int ty = ty0 + r * 8; tile[ty * 33 + tx] = src[ty * sstr + tx]; }
      __syncthreads();
#pragma unroll
      for (int r = 0; r < 4; r++) { int ty = ty0 + r * 8; dst[ty * dstr + tx] = f2bf(tile[tx * 33 + ty]); }
    } else if (j < 912) {              // x copies: traj row0, xbf, xbfT0
      int jj = j - 896;
      u16* xbfT0 = (u16*)(ws + WS_XBFT0);
#pragma unroll
      for (int k2 = 0; k2 < 8; k2++) {
        u32 e = (u32)jj * 2048u + (u32)(k2 * 256) + (u32)tid;
        float v = particles[e];
        traj[e] = v;
        u16 bv = f2bf(v);
        xbf[e] = bv;
        xbfT0[(e & 63u) * 512u + (e >> 6)] = bv;
      }
    } else {                           // hist zero (both parities) + betas
      u32* hc = (u32*)(ws + WS_COARSE);
      u32* hf = (u32*)(ws + WS_FINE);
      for (int k2 = 0; k2 < 16; k2++) { hc[k2 * 256 + tid] = 0u; hf[k2 * 256 + tid] = 0u; }
      if (tid == 0) {
        float sig[8]; float tot = 0.f;
        for (int k2 = 0; k2 < 8; k2++) { sig[k2] = 1.0f / (1.0f + __expf(-grid_t[k2])); tot += sig[k2]; }
        float cum = 0.f; BET[0] = 0.f;
        for (int k2 = 0; k2 < 8; k2++) { cum += sig[k2]; BET[k2 + 1] = cum / tot; }
      }
    }
    __syncthreads();
  }
  gsync(bar, 256u * (++rnd));

  // ================= P0b: te partial slabs (32 jobs) =========================
  if (b < 32) {
    int ii = b >> 2, kq = b & 3;
    float* g1 = sf;
    if (tid < 128) {
      int kglob = kq * 128 + tid;
      float s = 0.f;
#pragma unroll
      for (int sl = 0; sl < 8; sl++) s += G1P[(sl * 8 + ii) * 512 + kglob];
      g1[tid] = gelu_f(s);
    }
    __syncthreads();
    for (int h = 0; h < 2; h++) {
      int c = h * 256 + tid;
      float acc = (kq == 0) ? (t_b2[c] + in_b[c]) : 0.0f;
      const float* wp = t_W2 + (u32)(kq * 128) * 512u + c;
#pragma unroll 8
      for (int kk = 0; kk < 128; kk++) acc = fmaf(g1[kk], wp[kk * 512], acc);
      TEP[(kq * 8 + ii) * 512 + c] = acc;
    }
  }
  gsync(bar, 256u * (++rnd));

  // ================= main loop ==============================================
  const int rg = b >> 3, cg = b & 7;
  const int r0 = rg * 16;
  const int cA = cg * 64;

  for (int step = 0; step < 8; step++) {
    const int p = step & 1;
    u32* corP = (u32*)(ws + WS_COARSE) + p * 2048;
    u32* finP = (u32*)(ws + WS_FINE) + p * 2048;
    const u16* xT_in = (const u16*)(ws + (p ? WS_XBFT1 : WS_XBFT0));
    u16* xT_out = (u16*)(ws + (p ? WS_XBFT0 : WS_XBFT1));
    const float* x_old = traj + step * 32768;
    float* x_new = traj + (step + 1) * 32768;
    const float* noise_i = noises + step * 32768;

    // ---------------- PHASE 1: gram (norms in-block) + coarse hist ----------
    {
      su[tid] = 0u; su[256 + tid] = 0u;
      float* cnp = sf;         // [64][4]
      float* rnp = sf + 256;   // [16][4]
      float* cn_s = sf + 320;  // [64]
      float* rn_s = sf + 384;  // [16]
      {
        int c = tid >> 2, dq = tid & 3;
        const u16* xp = xbf + (cA + c) * 64 + dq * 16;
        float s = 0.f;
#pragma unroll
        for (int d = 0; d < 16; d++) { float v = bf2f(xp[d]); s = fmaf(v, v, s); }
        cnp[c * 4 + dq] = s;
      }
      if (tid < 64) {
        int r = tid >> 2, dq = tid & 3;
        const u16* xp = xbf + (r0 + r) * 64 + dq * 16;
        float s = 0.f;
#pragma unroll
        for (int d = 0; d < 16; d++) { float v = bf2f(xp[d]); s = fmaf(v, v, s); }
        rnp[r * 4 + dq] = s;
      }
      __syncthreads();
      if (tid < 64) cn_s[tid] = cnp[tid * 4] + cnp[tid * 4 + 1] + cnp[tid * 4 + 2] + cnp[tid * 4 + 3];
      else if (tid < 80) { int r = tid - 64; rn_s[r] = rnp[r * 4] + rnp[r * 4 + 1] + rnp[r * 4 + 2] + rnp[r * 4 + 3]; }
      __syncthreads();
      int c0 = cA + wv * 16;
      short8 a0 = *(const short8*)(xbf + (r0 + m) * 64 + q * 8);
      short8 a1 = *(const short8*)(xbf + (r0 + m) * 64 + 32 + q * 8);
      short8 b0 = *(const short8*)(xbf + (c0 + m) * 64 + q * 8);
      short8 b1 = *(const short8*)(xbf + (c0 + m) * 64 + 32 + q * 8);
      floatx4 acc = {0.f, 0.f, 0.f, 0.f};
      acc = MFMA(a0, b0, acc);
      acc = MFMA(a1, b1, acc);
      float nc = cn_s[wv * 16 + m];
#pragma unroll
      for (int rg2 = 0; rg2 < 4; rg2++) {
        int rl = q * 4 + rg2;
        float v = rn_s[rl] + nc - 2.0f * acc[rg2];
        d2g[(r0 + rl) * 512 + c0 + m] = v;
        int bin = (int)(v * 0.5f);
        bin = bin < 0 ? 0 : (bin > 511 ? 511 : bin);
        atomicAdd(&su[bin], 1u);
      }
      __syncthreads();
      u32 rep = (u32)(b & 3) * 512u;
      u32 v0 = su[tid]; if (v0) atomicAdd(&corP[rep + tid], v0);
      u32 v1 = su[256 + tid]; if (v1) atomicAdd(&corP[rep + 256 + tid], v1);
    }
    gsync(bar, 256u * (++rnd));

    // ---------------- PHASE 2: L0 + coarse median + fine hist ---------------
    u32 cb0, cb1, base0; float lo2, invbw, binw;
    {
      int c0 = cA + wv * 16;
      short8 a0 = *(const short8*)(xbf + (r0 + m) * 64 + q * 8);
      short8 a1 = *(const short8*)(xbf + (r0 + m) * 64 + 32 + q * 8);
      short8 b0 = *(const short8*)(inWT + (c0 + m) * 64 + q * 8);
      short8 b1 = *(const short8*)(inWT + (c0 + m) * 64 + 32 + q * 8);
      floatx4 acc = {0.f, 0.f, 0.f, 0.f};
      acc = MFMA(a0, b0, acc);
      acc = MFMA(a1, b1, acc);
      int col = c0 + m;
      float bv = TEP[step * 512 + col] + TEP[4096 + step * 512 + col]
               + TEP[8192 + step * 512 + col] + TEP[12288 + step * 512 + col];
#pragma unroll
      for (int rg2 = 0; rg2 < 4; rg2++)
        h0g[(r0 + q * 4 + rg2) * 512 + col] = f2bf(gelu_f(acc[rg2] + bv));

      // coarse scan (pairs: thread t handles bins 2t, 2t+1)
      u32 c0c = corP[2 * tid] + corP[512 + 2 * tid] + corP[1024 + 2 * tid] + corP[1536 + 2 * tid];
      u32 c1c = corP[2 * tid + 1] + corP[512 + 2 * tid + 1] + corP[1024 + 2 * tid + 1] + corP[1536 + 2 * tid + 1];
      su[tid] = c0c + c1c;
      __syncthreads();
      for (int off = 1; off < 256; off <<= 1) {
        u32 add = (tid >= off) ? su[tid - off] : 0u;
        __syncthreads(); su[tid] += add; __syncthreads();
      }
      u32 incl = su[tid], excl = incl - c0c - c1c;
#pragma unroll
      for (int tr = 0; tr < 2; tr++) {
        u32 R = 131071u + (u32)tr;
        if (R >= excl && R < excl + c0c) { su[300 + tr] = 2u * tid; if (tr == 0) su[304] = excl; }
        else if (R >= excl + c0c && R < incl) { su[300 + tr] = 2u * tid + 1u; if (tr == 0) su[304] = excl + c0c; }
      }
      __syncthreads();
      cb0 = su[300]; cb1 = su[301]; base0 = su[304];
      lo2 = (float)cb0 * 2.0f;
      float width = (float)(cb1 - cb0 + 1u) * 2.0f;
      invbw = 512.0f / width;
      binw = width * (1.0f / 512.0f);
      __syncthreads();
      su[tid] = 0u; su[256 + tid] = 0u;
      __syncthreads();
#pragma unroll
      for (int k2 = 0; k2 < 4; k2++) {
        int li = k2 * 256 + tid;
        int r = li >> 6, c = li & 63;
        float v = d2g[(r0 + r) * 512 + cA + c];
        int cbv = (int)(v * 0.5f); cbv = cbv < 0 ? 0 : (cbv > 511 ? 511 : cbv);
        if ((u32)cbv >= cb0 && (u32)cbv <= cb1) {
          int fb = (int)((v - lo2) * invbw);
          fb = fb < 0 ? 0 : (fb > 511 ? 511 : fb);
          atomicAdd(&su[fb], 1u);
        }
      }
      __syncthreads();
      u32 rep = (u32)(b & 3) * 512u;
      u32 v0 = su[tid]; if (v0) atomicAdd(&finP[rep + tid], v0);
      u32 v1 = su[256 + tid]; if (v1) atomicAdd(&finP[rep + 256 + tid], v1);
    }
    gsync(bar, 256u * (++rnd));

    // ---------------- PHASES 3-5: L1..L3 ------------------------------------
    {
      const u16* hin[3] = {h0g, h1g, h0g};
      u16* hout[3] = {h1g, h0g, h1g};
#pragma unroll 1
      for (int l = 0; l < 3; l++) {
        const u16* A = hin[l]; u16* O = hout[l];
        const u16* WT = hWT + l * 262144;
        int c0 = cA + wv * 16;
        floatx4 acc = {0.f, 0.f, 0.f, 0.f};
#pragma unroll
        for (int kk = 0; kk < 16; kk++) {
          short8 a = *(const short8*)(A + (r0 + m) * 512 + kk * 32 + q * 8);
          short8 bb = *(const short8*)(WT + (c0 + m) * 512 + kk * 32 + q * 8);
          acc = MFMA(a, bb, acc);
        }
        int col = c0 + m;
        float bv = h_b[l * 512 + col];
#pragma unroll
        for (int rg2 = 0; rg2 < 4; rg2++)
          O[(r0 + q * 4 + rg2) * 512 + col] = f2bf(gelu_f(acc[rg2] + bv));
        gsync(bar, 256u * (++rnd));
      }
    }

    // ---------------- PHASE 6: update (blocks 0..127) -----------------------
    if (b < 128) {
      const int urg = b >> 2, uct = b & 3;
      const int ur0 = urg * 16, uc0 = uct * 16;
      // fine median select
      {
        u32 f0 = finP[2 * tid] + finP[512 + 2 * tid] + finP[1024 + 2 * tid] + finP[1536 + 2 * tid];
        u32 f1 = finP[2 * tid + 1] + finP[512 + 2 * tid + 1] + finP[1024 + 2 * tid + 1] + finP[1536 + 2 * tid + 1];
        su[tid] = f0 + f1;
        __syncthreads();
        for (int off = 1; off < 256; off <<= 1) {
          u32 add = (tid >= off) ? su[tid - off] : 0u;
          __syncthreads(); su[tid] += add; __syncthreads();
        }
        u32 incl = su[tid], excl = incl - f0 - f1;
#pragma unroll
        for (int tr = 0; tr < 2; tr++) {
          u32 rl = 131071u + (u32)tr - base0;
          u32 fb = 0, flo = 0, cnt = 0; bool hit = false;
          if (rl >= excl && rl < excl + f0) { fb = 2u * tid; flo = excl; cnt = f0; hit = true; }
          else if (rl >= excl + f0 && rl < incl) { fb = 2u * tid + 1u; flo = excl + f0; cnt = f1; hit = true; }
          if (hit) {
            float d2v = lo2 + ((float)fb + ((float)(rl - flo) + 0.5f) / (float)cnt) * binw;
            medf[tr] = sqrtf(fmaxf(d2v, 1e-12f));
          }
        }
        __syncthreads();
        if (tid == 0) {
          float md = 0.5f * (medf[0] + medf[1]);
          medf[2] = 6.2383246250395075f / (md * md);   // log(512)/h_t
        }
        __syncthreads();
      }
      float inv_ht = medf[2];
      // score + S1 GEMMs, wave wv = K-slice of 4 kk
      floatx4 accS = {0.f, 0.f, 0.f, 0.f}, accR = {0.f, 0.f, 0.f, 0.f};
      float s0 = 0.f;
#pragma unroll
      for (int kk = wv * 4; kk < wv * 4 + 4; kk++) {
        short8 a = *(const short8*)(h1g + (ur0 + m) * 512 + kk * 32 + q * 8);
        short8 bw = *(const short8*)(outWT + (uc0 + m) * 512 + kk * 32 + q * 8);
        accS = MFMA(a, bw, accS);
        const float4* dr = (const float4*)(d2g + (ur0 + m) * 512 + kk * 32 + q * 8);
        float4 dv0 = dr[0], dv1 = dr[1];
        float dvals[8] = {dv0.x, dv0.y, dv0.z, dv0.w, dv1.x, dv1.y, dv1.z, dv1.w};
        short8 wf;
#pragma unroll
        for (int jj = 0; jj < 8; jj++) {
          float w = __expf(-dvals[jj] * inv_ht);
          s0 += w;
          wf[jj] = (short)f2bf(w);
        }
        short8 bx = *(const short8*)(xT_in + (uc0 + m) * 512 + kk * 32 + q * 8);
        accR = MFMA(wf, bx, accR);
      }
      s0 += __shfl_xor(s0, 16);
      s0 += __shfl_xor(s0, 32);
      float* combS = sf;           // [3][64][4]
      float* combR = sf + 768;
      float* sc_s = sf + 1536;     // [16][16]
      float* s1_s = sf + 1792;
      float* s0p  = sf + 2048;     // [16][4]
      if (wv) {
#pragma unroll
        for (int rg2 = 0; rg2 < 4; rg2++) {
          combS[((wv - 1) * 64 + lane) * 4 + rg2] = accS[rg2];
          combR[((wv - 1) * 64 + lane) * 4 + rg2] = accR[rg2];
        }
      }
      if (q == 0) s0p[m * 4 + wv] = s0;
      __syncthreads();
      if (wv == 0) {
        float ob = out_b[uc0 + m];
#pragma unroll
        for (int rg2 = 0; rg2 < 4; rg2++) {
          float aS = accS[rg2], aR = accR[rg2];
#pragma unroll
          for (int w2 = 0; w2 < 3; w2++) {
            aS += combS[(w2 * 64 + lane) * 4 + rg2];
            aR += combR[(w2 * 64 + lane) * 4 + rg2];
          }
          sc_s[(q * 4 + rg2) * 16 + m] = aS + ob;
          s1_s[(q * 4 + rg2) * 16 + m] = aR;
        }
      }
      __syncthreads();
      float* comp = sf;        // [16][8] (combS dead)
      float* w8   = sf + 128;  // [16][8]
      float* wm   = sf + 256;  // [16][16]
      if (tid < 128) {
        int r = tid >> 3, mm = tid & 7;
        const float* xr = x_old + (ur0 + r) * 64;
        const float* mr = mu + mm * 64;
        float s = 0.f;
#pragma unroll 8
        for (int d = 0; d < 64; d++) { float df = xr[d] - mr[d]; s = fmaf(df, df, s); }
        comp[r * 8 + mm] = -0.5f * s;
      }
      __syncthreads();
      if (tid < 16) {
        float mx = comp[tid * 8];
        for (int j2 = 1; j2 < 8; j2++) mx = fmaxf(mx, comp[tid * 8 + j2]);
        float sm = 0.f; float e[8];
        for (int j2 = 0; j2 < 8; j2++) { e[j2] = __expf(comp[tid * 8 + j2] - mx); sm += e[j2]; }
        float inv = 1.0f / sm;
        for (int j2 = 0; j2 < 8; j2++) w8[tid * 8 + j2] = e[j2] * inv;
      }
      __syncthreads();
      {
        int r = tid >> 4, dl = tid & 15;
        float a2 = 0.f;
#pragma unroll
        for (int mm = 0; mm < 8; mm++) a2 = fmaf(w8[r * 8 + mm], mu[mm * 64 + uc0 + dl], a2);
        wm[r * 16 + dl] = a2;
      }
      __syncthreads();
      {
        float tb = BET[step];
        float dt = eps[0];
        float sq = sqrtf(2.0f * dt);
        int r = tid >> 4, dl = tid & 15;
        int grow = ur0 + r, d = uc0 + dl;
        float s0r = s0p[r * 4] + s0p[r * 4 + 1] + s0p[r * 4 + 2] + s0p[r * 4 + 3];
        float cR = -0.1f * inv_ht;
        float xv = x_old[grow * 64 + d];
        float g = -xv + tb * wm[r * 16 + dl];                // grad log pi
        float rep = cR * (xv * s0r - s1_s[r * 16 + dl]);     // repel(x_old)
        float nv = xv + dt * (g - sc_s[r * 16 + dl]) - dt * rep + sq * noise_i[grow * 64 + d];
        x_new[grow * 64 + d] = nv;
        u16 bv = f2bf(nv);
        xbf[grow * 64 + d] = bv;
        xT_out[d * 512 + grow] = bv;
      }
    } else {
      // zero other-parity hists for next step
      int bb = b - 128;
      u32* hcO = (u32*)(ws + WS_COARSE) + (p ^ 1) * 2048;
      u32* hfO = (u32*)(ws + WS_FINE) + (p ^ 1) * 2048;
      if (tid < 32) {
        int w = bb * 32 + tid;
        if (w < 2048) hcO[w] = 0u; else hfO[w - 2048] = 0u;
      }
    }
    gsync(bar, 256u * (++rnd));
  }
}

extern "C" void kernel_launch(void* const* d_in, const int* in_sizes, int n_in,
                              void* d_out, int out_size, void* d_ws, size_t ws_size,
                              hipStream_t stream) {
  (void)in_sizes; (void)n_in; (void)out_size; (void)ws_size;
  const float* particles    = (const float*)d_in[0];
  const float* noises       = (const float*)d_in[1];
  const float* grid_t       = (const float*)d_in[2];
  const float* eps          = (const float*)d_in[3];
  const float* target_means = (const float*)d_in[4];
  const float* phase        = (const float*)d_in[5];
  const float* in_W         = (const float*)d_in[6];
  const float* in_b         = (const float*)d_in[7];
  const float* t_W1         = (const float*)d_in[8];
  const float* t_b1         = (const float*)d_in[9];
  const float* t_W2         = (const float*)d_in[10];
  const float* t_b2         = (const float*)d_in[11];
  const float* h_W          = (const float*)d_in[12];
  const float* h_b          = (const float*)d_in[13];
  const float* out_W        = (const float*)d_in[14];
  const float* out_b        = (const float*)d_in[15];
  float* traj = (float*)d_out;
  char* ws = (char*)d_ws;

  hipMemsetAsync(ws + WS_BAR, 0, 64, stream);

  void* args[] = {
    (void*)&particles, (void*)&noises, (void*)&grid_t, (void*)&eps,
    (void*)&target_means, (void*)&phase, (void*)&in_W, (void*)&in_b,
    (void*)&t_W1, (void*)&t_b1, (void*)&t_W2, (void*)&t_b2,
    (void*)&h_W, (void*)&h_b, (void*)&out_W, (void*)&out_b,
    (void*)&traj, (void*)&ws
  };
  hipLaunchCooperativeKernel((void*)mega, dim3(256), dim3(256), args, 0, stream);
}

// Round 5
// 610.893 us; speedup vs baseline: 2.4963x; 2.4963x over previous
//
#include <hip/hip_runtime.h>
#include <math.h>

// CMCD sampler: persistent cooperative kernel, 256 blocks x 256 threads.
// R5: fence-free steady state. Read-only data (weights/TEP) = plain cached
// loads, flushed once by 2 heavy prep syncs, never invalidated again.
// Cross-block mutable data (h, d2, x, hists) = sc0 sc1 (system-scope,
// L1/L2-bypass) batched asm loads/stores -> no buffer_inv/wbl2 in the loop.
// Barrier = relaxed atomic counter + sc0sc1 spin load. 5 syncs/step, 42 total.

typedef __attribute__((ext_vector_type(8))) short short8;
typedef __attribute__((ext_vector_type(4))) float floatx4;
typedef __attribute__((ext_vector_type(2))) unsigned int u32x2;
typedef unsigned int u32;
typedef unsigned short u16;

// ---- workspace byte offsets (~4.23 MB) ----
#define WS_BAR     0u         // u32 barrier counter (memset 0 each launch)
#define WS_BETAS   64u        // f32[16]
#define WS_COARSE  128u       // u32[2 parity][4 rep][512]
#define WS_FINE    16512u     // u32[2 parity][4 rep][512]
#define WS_TEP     32896u     // f32[4 kq][8 i][512] te partials
#define WS_G1P     98432u     // f32[8 slice][8 i][512] t-MLP pre-act partials
#define WS_XBF     229504u    // u16[512*64]  x bf16 row-major
#define WS_XBFT0   295040u    // u16[64*512]  x^T bf16 parity 0
#define WS_XBFT1   360576u    // u16[64*512]  x^T bf16 parity 1
#define WS_INWT    426112u    // u16[512*64]  in_W^T
#define WS_OUTWT   491648u    // u16[64*512]  out_W^T
#define WS_HWT     557184u    // u16[3*512*512] h_W^T
#define WS_D2      2130048u   // f32[512*512]
#define WS_H0      3178624u   // u16[512*512] h ping
#define WS_H1      3702912u   // u16[512*512] h pong

__device__ __forceinline__ u16 f2bf(float f) {
  u32 u = __float_as_uint(f);
  u32 r = u + 0x7FFFu + ((u >> 16) & 1u);
  return (u16)(r >> 16);
}
__device__ __forceinline__ float bf2f(u16 v) {
  return __uint_as_float(((u32)v) << 16);
}

// tanh-approx gelu (jax.nn.gelu default approximate=True)
__device__ __forceinline__ float gelu_f(float x) {
  float y = 0.7978845608028654f * (x + 0.044715f * x * x * x);
  float ay = fabsf(y);
  float e = __expf(-2.0f * ay);
  float t = (1.0f - e) / (1.0f + e);
  t = (y < 0.0f) ? -t : t;
  return 0.5f * x * (1.0f + t);
}

// ======================= sc0 sc1 (system-scope) access ======================
__device__ __forceinline__ u32 scld_u32(const u32* p) {
  u32 r;
  asm volatile("global_load_dword %0, %1, off sc0 sc1\n\ts_waitcnt vmcnt(0)"
               : "=v"(r) : "v"(p) : "memory");
  return r;
}
__device__ __forceinline__ void scld_f4(const float* p, floatx4& r) {
  asm volatile("global_load_dwordx4 %0, %1, off sc0 sc1\n\ts_waitcnt vmcnt(0)"
               : "=v"(r) : "v"(p) : "memory");
}
// gram: A-pair (base pa, +64B) and B-pair (base pb, +64B) in one round trip
__device__ __forceinline__ void scld_gram(const u16* pa, const u16* pb,
                                          short8& a0, short8& a1, short8& b0, short8& b1) {
  asm volatile(
    "global_load_dwordx4 %0, %4, off sc0 sc1\n\t"
    "global_load_dwordx4 %1, %4, off offset:64 sc0 sc1\n\t"
    "global_load_dwordx4 %2, %5, off sc0 sc1\n\t"
    "global_load_dwordx4 %3, %5, off offset:64 sc0 sc1\n\t"
    "s_waitcnt vmcnt(0)"
    : "=&v"(a0), "=&v"(a1), "=&v"(b0), "=&v"(b1)
    : "v"(pa), "v"(pb) : "memory");
}
// 16 x b128 at stride 64B (full K=512 A-fragment row), one round trip
__device__ __forceinline__ void scld16_64(const u16* p, short8* a) {
  asm volatile(
    "global_load_dwordx4 %0, %16, off sc0 sc1\n\t"
    "global_load_dwordx4 %1, %16, off offset:64 sc0 sc1\n\t"
    "global_load_dwordx4 %2, %16, off offset:128 sc0 sc1\n\t"
    "global_load_dwordx4 %3, %16, off offset:192 sc0 sc1\n\t"
    "global_load_dwordx4 %4, %16, off offset:256 sc0 sc1\n\t"
    "global_load_dwordx4 %5, %16, off offset:320 sc0 sc1\n\t"
    "global_load_dwordx4 %6, %16, off offset:384 sc0 sc1\n\t"
    "global_load_dwordx4 %7, %16, off offset:448 sc0 sc1\n\t"
    "global_load_dwordx4 %8, %16, off offset:512 sc0 sc1\n\t"
    "global_load_dwordx4 %9, %16, off offset:576 sc0 sc1\n\t"
    "global_load_dwordx4 %10, %16, off offset:640 sc0 sc1\n\t"
    "global_load_dwordx4 %11, %16, off offset:704 sc0 sc1\n\t"
    "global_load_dwordx4 %12, %16, off offset:768 sc0 sc1\n\t"
    "global_load_dwordx4 %13, %16, off offset:832 sc0 sc1\n\t"
    "global_load_dwordx4 %14, %16, off offset:896 sc0 sc1\n\t"
    "global_load_dwordx4 %15, %16, off offset:960 sc0 sc1\n\t"
    "s_waitcnt vmcnt(0)"
    : "=&v"(a[0]), "=&v"(a[1]), "=&v"(a[2]), "=&v"(a[3]),
      "=&v"(a[4]), "=&v"(a[5]), "=&v"(a[6]), "=&v"(a[7]),
      "=&v"(a[8]), "=&v"(a[9]), "=&v"(a[10]), "=&v"(a[11]),
      "=&v"(a[12]), "=&v"(a[13]), "=&v"(a[14]), "=&v"(a[15])
    : "v"(p) : "memory");
}
// 4 x b128 at stride 64B
__device__ __forceinline__ void scld4_64(const u16* p, short8& r0, short8& r1,
                                         short8& r2, short8& r3) {
  asm volatile(
    "global_load_dwordx4 %0, %4, off sc0 sc1\n\t"
    "global_load_dwordx4 %1, %4, off offset:64 sc0 sc1\n\t"
    "global_load_dwordx4 %2, %4, off offset:128 sc0 sc1\n\t"
    "global_load_dwordx4 %3, %4, off offset:192 sc0 sc1\n\t"
    "s_waitcnt vmcnt(0)"
    : "=&v"(r0), "=&v"(r1), "=&v"(r2), "=&v"(r3)
    : "v"(p) : "memory");
}
// d2 A-pattern for 4 kk: offsets {0,16, 128,144, 256,272, 384,400} bytes
__device__ __forceinline__ void scld8_d2(const float* p, floatx4* d) {
  asm volatile(
    "global_load_dwordx4 %0, %8, off sc0 sc1\n\t"
    "global_load_dwordx4 %1, %8, off offset:16 sc0 sc1\n\t"
    "global_load_dwordx4 %2, %8, off offset:128 sc0 sc1\n\t"
    "global_load_dwordx4 %3, %8, off offset:144 sc0 sc1\n\t"
    "global_load_dwordx4 %4, %8, off offset:256 sc0 sc1\n\t"
    "global_load_dwordx4 %5, %8, off offset:272 sc0 sc1\n\t"
    "global_load_dwordx4 %6, %8, off offset:384 sc0 sc1\n\t"
    "global_load_dwordx4 %7, %8, off offset:400 sc0 sc1\n\t"
    "s_waitcnt vmcnt(0)"
    : "=&v"(d[0]), "=&v"(d[1]), "=&v"(d[2]), "=&v"(d[3]),
      "=&v"(d[4]), "=&v"(d[5]), "=&v"(d[6]), "=&v"(d[7])
    : "v"(p) : "memory");
}
// 4 x dwordx2 (hist replica pair reads)
__device__ __forceinline__ void scld4_u2(const u32* p0, const u32* p1,
                                         const u32* p2, const u32* p3,
                                         u32x2& r0, u32x2& r1, u32x2& r2, u32x2& r3) {
  asm volatile(
    "global_load_dwordx2 %0, %4, off sc0 sc1\n\t"
    "global_load_dwordx2 %1, %5, off sc0 sc1\n\t"
    "global_load_dwordx2 %2, %6, off sc0 sc1\n\t"
    "global_load_dwordx2 %3, %7, off sc0 sc1\n\t"
    "s_waitcnt vmcnt(0)"
    : "=&v"(r0), "=&v"(r1), "=&v"(r2), "=&v"(r3)
    : "v"(p0), "v"(p1), "v"(p2), "v"(p3) : "memory");
}
__device__ __forceinline__ void scst_f32(float* p, float v) {
  asm volatile("global_store_dword %0, %1, off sc0 sc1" :: "v"(p), "v"(v) : "memory");
}
__device__ __forceinline__ void scst_u32(u32* p, u32 v) {
  asm volatile("global_store_dword %0, %1, off sc0 sc1" :: "v"(p), "v"(v) : "memory");
}
__device__ __forceinline__ void scst_u16(u16* p, u16 v) {
  u32 x = v;
  asm volatile("global_store_short %0, %1, off sc0 sc1" :: "v"(p), "v"(x) : "memory");
}

// grid barrier: every wave drains its own vmcnt (sc-stores!), then relaxed
// arrive + sc0sc1 spin (NO acquire/release fences in the steady state).
// heavy=true (prep only): threadfence release/acquire to flush plain-written
// read-only data (weights/TEP) to L3 once.
__device__ __forceinline__ void gsync(u32* bar, u32 target, bool heavy) {
  asm volatile("s_waitcnt vmcnt(0)" ::: "memory");
  __syncthreads();
  if (threadIdx.x == 0) {
    if (heavy) __threadfence();
    __hip_atomic_fetch_add(bar, 1u, __ATOMIC_RELAXED, __HIP_MEMORY_SCOPE_AGENT);
    while (scld_u32(bar) < target) __builtin_amdgcn_s_sleep(4);
    if (heavy) __threadfence();
  }
  __syncthreads();
}

#define MFMA(a, b, c) __builtin_amdgcn_mfma_f32_16x16x32_bf16((a), (b), (c), 0, 0, 0)

__global__ __launch_bounds__(256) void mega(
    const float* __restrict__ particles, const float* __restrict__ noises,
    const float* __restrict__ grid_t, const float* __restrict__ eps,
    const float* __restrict__ mu, const float* __restrict__ phase,
    const float* __restrict__ in_W, const float* __restrict__ in_b,
    const float* __restrict__ t_W1, const float* __restrict__ t_b1,
    const float* __restrict__ t_W2, const float* __restrict__ t_b2,
    const float* __restrict__ h_W, const float* __restrict__ h_b,
    const float* __restrict__ out_W, const float* __restrict__ out_b,
    float* __restrict__ traj, char* __restrict__ ws)
{
  __shared__ u32 su[512];
  __shared__ float sf[3200];
  __shared__ float medf[4];
  __shared__ float rn_s[16];

  u32* bar = (u32*)(ws + WS_BAR);
  float* BET = (float*)(ws + WS_BETAS);
  float* TEP = (float*)(ws + WS_TEP);
  float* G1P = (float*)(ws + WS_G1P);
  u16* xbf = (u16*)(ws + WS_XBF);
  u16* inWT = (u16*)(ws + WS_INWT);
  u16* outWT = (u16*)(ws + WS_OUTWT);
  u16* hWT = (u16*)(ws + WS_HWT);
  float* d2g = (float*)(ws + WS_D2);
  u16* h0g = (u16*)(ws + WS_H0);
  u16* h1g = (u16*)(ws + WS_H1);

  const int b = blockIdx.x;
  const int tid = threadIdx.x;
  const int wv = tid >> 6, lane = tid & 63;
  const int m = lane & 15, q = lane >> 4;
  u32 rnd = 0;

  // ================= P0: prep jobs (plain stores; heavy-synced) =============
  for (int j = b; j < 913; j += 256) {
    if (j < 64) {                      // t-MLP pre-act partial, K-chain 128
      int slice = j >> 3, ii = j & 7;
      float* temb = sf;
      if (tid < 128) {
        int kglob = slice * 128 + tid;
        int kc = kglob & 511;
        float cf = 0.1f + (float)kc * (99.9f / 511.0f);
        float e = cf * (float)ii + phase[kc];
        temb[tid] = (kglob < 512) ? sinf(e) : cosf(e);
      }
      __syncthreads();
      for (int h = 0; h < 2; h++) {
        int c = h * 256 + tid;
        float acc = (slice == 0) ? t_b1[c] : 0.0f;
        const float* wp = t_W1 + (u32)(slice * 128) * 512u + c;
#pragma unroll 8
        for (int kk = 0; kk < 128; kk++) acc = fmaf(temb[kk], wp[kk * 512], acc);
        G1P[(slice * 8 + ii) * 512 + c] = acc;
      }
    } else if (j < 896) {              // LDS-tiled weight transposes -> bf16
      float* tile = sf;                // [32][33]
      int tx = tid & 31, ty0 = tid >> 5;
      const float* src; u16* dst; int sstr, dstr;
      if (j < 832) {
        int ti = j - 64; int l = ti >> 8, rem = ti & 255, kt = rem >> 4, ct = rem & 15;
        src = h_W + l * 262144 + kt * 32 * 512 + ct * 32; sstr = 512;
        dst = hWT + l * 262144 + ct * 32 * 512 + kt * 32; dstr = 512;
      } else if (j < 864) {
        int ti = j - 832; int kt = ti >> 4, ct = ti & 15;
        src = in_W + kt * 32 * 512 + ct * 32; sstr = 512;
        dst = inWT + ct * 32 * 64 + kt * 32; dstr = 64;
      } else {
        int ti = j - 864; int ct = ti >> 4, kt = ti & 15;
        src = out_W + kt * 32 * 64 + ct * 32; sstr = 64;
        dst = outWT + ct * 32 * 512 + kt * 32; dstr = 512;
      }
#pragma unroll
      for (int r = 0; r < 4; r++) { int ty = ty0 + r * 8; tile[ty * 33 + tx] = src[ty * sstr + tx]; }
      __syncthreads();
#pragma unroll
      for (int r = 0; r < 4; r++) { int ty = ty0 + r * 8; dst[ty * dstr + tx] = f2bf(tile[tx * 33 + ty]); }
    } else if (j < 912) {              // x copies: traj row0, xbf, xbfT0
      int jj = j - 896;
      u16* xbfT0 = (u16*)(ws + WS_XBFT0);
#pragma unroll
      for (int k2 = 0; k2 < 8; k2++) {
        u32 e = (u32)jj * 2048u + (u32)(k2 * 256) + (u32)tid;
        float v = particles[e];
        traj[e] = v;
        u16 bv = f2bf(v);
        xbf[e] = bv;
        xbfT0[(e & 63u) * 512u + (e >> 6)] = bv;
      }
    } else {                           // hist zero (both parities) + betas
      u32* hc = (u32*)(ws + WS_COARSE);
      u32* hf = (u32*)(ws + WS_FINE);
      for (int k2 = 0; k2 < 16; k2++) { hc[k2 * 256 + tid] = 0u; hf[k2 * 256 + tid] = 0u; }
      if (tid == 0) {
        float sig[8]; float tot = 0.f;
        for (int k2 = 0; k2 < 8; k2++) { sig[k2] = 1.0f / (1.0f + __expf(-grid_t[k2])); tot += sig[k2]; }
        float cum = 0.f; BET[0] = 0.f;
        for (int k2 = 0; k2 < 8; k2++) { cum += sig[k2]; BET[k2 + 1] = cum / tot; }
      }
    }
    __syncthreads();
  }
  gsync(bar, 256u * (++rnd), true);    // HEAVY

  // ================= P0b: te partial slabs (32 jobs; heavy-synced) ==========
  if (b < 32) {
    int ii = b >> 2, kq = b & 3;
    float* g1 = sf;
    if (tid < 128) {
      int kglob = kq * 128 + tid;
      float s = 0.f;
#pragma unroll
      for (int sl = 0; sl < 8; sl++) s += G1P[(sl * 8 + ii) * 512 + kglob];
      g1[tid] = gelu_f(s);
    }
    __syncthreads();
    for (int h = 0; h < 2; h++) {
      int c = h * 256 + tid;
      float acc = (kq == 0) ? (t_b2[c] + in_b[c]) : 0.0f;
      const float* wp = t_W2 + (u32)(kq * 128) * 512u + c;
#pragma unroll 8
      for (int kk = 0; kk < 128; kk++) acc = fmaf(g1[kk], wp[kk * 512], acc);
      TEP[(kq * 8 + ii) * 512 + c] = acc;
    }
  }
  gsync(bar, 256u * (++rnd), true);    // HEAVY — after this, weights/TEP/BET
                                       // are read-only & stay L2-cached forever

  // ================= main loop ==============================================
  const int rg = b >> 3, cg = b & 7;
  const int r0 = rg * 16;
  const int cA = cg * 64;

  for (int step = 0; step < 8; step++) {
    const int p = step & 1;
    u32* corP = (u32*)(ws + WS_COARSE) + p * 2048;
    u32* finP = (u32*)(ws + WS_FINE) + p * 2048;
    const u16* xT_in = (const u16*)(ws + (p ? WS_XBFT1 : WS_XBFT0));
    u16* xT_out = (u16*)(ws + (p ? WS_XBFT0 : WS_XBFT1));
    const float* x_old = traj + step * 32768;
    float* x_new = traj + (step + 1) * 32768;
    const float* noise_i = noises + step * 32768;

    // -------- P1: gram (norms from frags) + coarse hist + L0 ----------------
    floatx4 d2r;
    {
      int c0 = cA + wv * 16;
      short8 a0, a1, b0, b1;
      scld_gram(xbf + (r0 + m) * 64 + q * 8, xbf + (c0 + m) * 64 + q * 8, a0, a1, b0, b1);
      float rp = 0.f, cp = 0.f;
#pragma unroll
      for (int jj = 0; jj < 8; jj++) {
        float v;
        v = bf2f((u16)a0[jj]); rp = fmaf(v, v, rp);
        v = bf2f((u16)a1[jj]); rp = fmaf(v, v, rp);
        v = bf2f((u16)b0[jj]); cp = fmaf(v, v, cp);
        v = bf2f((u16)b1[jj]); cp = fmaf(v, v, cp);
      }
      rp += __shfl_xor(rp, 16); rp += __shfl_xor(rp, 32);
      cp += __shfl_xor(cp, 16); cp += __shfl_xor(cp, 32);
      if (wv == 0 && q == 0) rn_s[m] = rp;
      su[tid] = 0u; su[256 + tid] = 0u;
      __syncthreads();
      floatx4 acc = {0.f, 0.f, 0.f, 0.f};
      acc = MFMA(a0, b0, acc);
      acc = MFMA(a1, b1, acc);
#pragma unroll
      for (int rg2 = 0; rg2 < 4; rg2++) {
        int rl = q * 4 + rg2;
        float v = rn_s[rl] + cp - 2.0f * acc[rg2];
        d2r[rg2] = v;
        scst_f32(d2g + (r0 + rl) * 512 + c0 + m, v);
        int bin = (int)(v * 0.5f);
        bin = bin < 0 ? 0 : (bin > 511 ? 511 : bin);
        atomicAdd(&su[bin], 1u);
      }
      __syncthreads();
      u32 rep = (u32)(b & 3) * 512u;
      u32 v0 = su[tid]; if (v0) atomicAdd(&corP[rep + tid], v0);
      u32 v1 = su[256 + tid]; if (v1) atomicAdd(&corP[rep + 256 + tid], v1);
      // L0 (weights cached, bias from TEP cached)
      short8 w0 = *(const short8*)(inWT + (c0 + m) * 64 + q * 8);
      short8 w1 = *(const short8*)(inWT + (c0 + m) * 64 + 32 + q * 8);
      floatx4 fac = {0.f, 0.f, 0.f, 0.f};
      fac = MFMA(a0, w0, fac);
      fac = MFMA(a1, w1, fac);
      int col = c0 + m;
      float bv = TEP[step * 512 + col] + TEP[4096 + step * 512 + col]
               + TEP[8192 + step * 512 + col] + TEP[12288 + step * 512 + col];
#pragma unroll
      for (int rg2 = 0; rg2 < 4; rg2++)
        scst_u16(h0g + (r0 + q * 4 + rg2) * 512 + col, f2bf(gelu_f(fac[rg2] + bv)));
    }
    gsync(bar, 256u * (++rnd), false);

    // -------- P2: L1 + coarse-median scan + fine hist -----------------------
    u32 base0; float lo2, invbw, binw;
    {
      int c0 = cA + wv * 16;
      short8 a[16];
      scld16_64(h0g + (r0 + m) * 512 + q * 8, a);
      floatx4 acc = {0.f, 0.f, 0.f, 0.f};
#pragma unroll
      for (int kk = 0; kk < 16; kk++) {
        short8 bb = *(const short8*)(hWT + (c0 + m) * 512 + kk * 32 + q * 8);
        acc = MFMA(a[kk], bb, acc);
      }
      int col = c0 + m;
      float bv = h_b[col];
#pragma unroll
      for (int rg2 = 0; rg2 < 4; rg2++)
        scst_u16(h1g + (r0 + q * 4 + rg2) * 512 + col, f2bf(gelu_f(acc[rg2] + bv)));

      // coarse scan (pairs: thread t handles bins 2t, 2t+1)
      u32x2 h0p, h1p, h2p, h3p;
      scld4_u2(&corP[2 * tid], &corP[512 + 2 * tid], &corP[1024 + 2 * tid], &corP[1536 + 2 * tid],
               h0p, h1p, h2p, h3p);
      u32 c0c = h0p.x + h1p.x + h2p.x + h3p.x;
      u32 c1c = h0p.y + h1p.y + h2p.y + h3p.y;
      su[tid] = c0c + c1c;
      __syncthreads();
      for (int off = 1; off < 256; off <<= 1) {
        u32 add = (tid >= off) ? su[tid - off] : 0u;
        __syncthreads(); su[tid] += add; __syncthreads();
      }
      u32 incl = su[tid], excl = incl - c0c - c1c;
#pragma unroll
      for (int tr = 0; tr < 2; tr++) {
        u32 R = 131071u + (u32)tr;
        if (R >= excl && R < excl + c0c) { su[300 + tr] = 2u * tid; if (tr == 0) su[304] = excl; }
        else if (R >= excl + c0c && R < incl) { su[300 + tr] = 2u * tid + 1u; if (tr == 0) su[304] = excl + c0c; }
      }
      __syncthreads();
      u32 cb0 = su[300], cb1 = su[301];
      base0 = su[304];
      lo2 = (float)cb0 * 2.0f;
      float width = (float)(cb1 - cb0 + 1u) * 2.0f;
      invbw = 512.0f / width;
      binw = width * (1.0f / 512.0f);
      __syncthreads();
      su[tid] = 0u; su[256 + tid] = 0u;
      __syncthreads();
#pragma unroll
      for (int rg2 = 0; rg2 < 4; rg2++) {
        float v = d2r[rg2];
        int cbv = (int)(v * 0.5f); cbv = cbv < 0 ? 0 : (cbv > 511 ? 511 : cbv);
        if ((u32)cbv >= cb0 && (u32)cbv <= cb1) {
          int fb = (int)((v - lo2) * invbw);
          fb = fb < 0 ? 0 : (fb > 511 ? 511 : fb);
          atomicAdd(&su[fb], 1u);
        }
      }
      __syncthreads();
      u32 rep = (u32)(b & 3) * 512u;
      u32 v0 = su[tid]; if (v0) atomicAdd(&finP[rep + tid], v0);
      u32 v1 = su[256 + tid]; if (v1) atomicAdd(&finP[rep + 256 + tid], v1);
    }
    gsync(bar, 256u * (++rnd), false);

    // -------- P3, P4: L2, L3 ------------------------------------------------
#pragma unroll 1
    for (int l = 1; l < 3; l++) {
      const u16* A = (l == 1) ? h1g : h0g;
      u16* O = (l == 1) ? h0g : h1g;
      const u16* WT = hWT + l * 262144;
      int c0 = cA + wv * 16;
      short8 a[16];
      scld16_64(A + (r0 + m) * 512 + q * 8, a);
      floatx4 acc = {0.f, 0.f, 0.f, 0.f};
#pragma unroll
      for (int kk = 0; kk < 16; kk++) {
        short8 bb = *(const short8*)(WT + (c0 + m) * 512 + kk * 32 + q * 8);
        acc = MFMA(a[kk], bb, acc);
      }
      int col = c0 + m;
      float bv = h_b[l * 512 + col];
#pragma unroll
      for (int rg2 = 0; rg2 < 4; rg2++)
        scst_u16(O + (r0 + q * 4 + rg2) * 512 + col, f2bf(gelu_f(acc[rg2] + bv)));
      gsync(bar, 256u * (++rnd), false);
    }
    // h3 = h1g

    // -------- P5: update (blocks 0..127) + hist-zero (128..255) -------------
    if (b < 128) {
      const int urg = b >> 2, uct = b & 3;
      const int ur0 = urg * 16, uc0 = uct * 16;
      // stage x_old rows into LDS
      float* xold = sf + 2112;   // [16][64]
      {
        int r = tid >> 4, c4 = tid & 15;
        floatx4 xv4;
        scld_f4(x_old + (ur0 + r) * 64 + c4 * 4, xv4);
        *(floatx4*)(xold + r * 64 + c4 * 4) = xv4;
      }
      // fine median select
      {
        u32x2 f0p, f1p, f2p, f3p;
        scld4_u2(&finP[2 * tid], &finP[512 + 2 * tid], &finP[1024 + 2 * tid], &finP[1536 + 2 * tid],
                 f0p, f1p, f2p, f3p);
        u32 f0 = f0p.x + f1p.x + f2p.x + f3p.x;
        u32 f1 = f0p.y + f1p.y + f2p.y + f3p.y;
        su[tid] = f0 + f1;
        __syncthreads();
        for (int off = 1; off < 256; off <<= 1) {
          u32 add = (tid >= off) ? su[tid - off] : 0u;
          __syncthreads(); su[tid] += add; __syncthreads();
        }
        u32 incl = su[tid], excl = incl - f0 - f1;
#pragma unroll
        for (int tr = 0; tr < 2; tr++) {
          u32 rl = 131071u + (u32)tr - base0;
          u32 fb = 0, flo = 0, cnt = 0; bool hit = false;
          if (rl >= excl && rl < excl + f0) { fb = 2u * tid; flo = excl; cnt = f0; hit = true; }
          else if (rl >= excl + f0 && rl < incl) { fb = 2u * tid + 1u; flo = excl + f0; cnt = f1; hit = true; }
          if (hit) {
            float d2v = lo2 + ((float)fb + ((float)(rl - flo) + 0.5f) / (float)cnt) * binw;
            medf[tr] = sqrtf(fmaxf(d2v, 1e-12f));
          }
        }
        __syncthreads();
        if (tid == 0) {
          float md = 0.5f * (medf[0] + medf[1]);
          medf[2] = 6.2383246250395075f / (md * md);   // log(512)/h_t
        }
        __syncthreads();
      }
      float inv_ht = medf[2];
      // score + S1 GEMMs, wave wv = K-slice of 4 kk
      short8 ha0, ha1, ha2, ha3, xb0, xb1, xb2, xb3;
      scld4_64(h1g + (ur0 + m) * 512 + wv * 128 + q * 8, ha0, ha1, ha2, ha3);
      scld4_64(xT_in + (uc0 + m) * 512 + wv * 128 + q * 8, xb0, xb1, xb2, xb3);
      floatx4 dv[8];
      scld8_d2(d2g + (ur0 + m) * 512 + wv * 128 + q * 8, dv);
      floatx4 accS = {0.f, 0.f, 0.f, 0.f}, accR = {0.f, 0.f, 0.f, 0.f};
      float s0 = 0.f;
      short8 has[4] = {ha0, ha1, ha2, ha3};
      short8 xbs[4] = {xb0, xb1, xb2, xb3};
#pragma unroll
      for (int kl = 0; kl < 4; kl++) {
        int kk = wv * 4 + kl;
        short8 bw = *(const short8*)(outWT + (uc0 + m) * 512 + kk * 32 + q * 8);
        accS = MFMA(has[kl], bw, accS);
        short8 wf;
#pragma unroll
        for (int jj = 0; jj < 8; jj++) {
          float w = __expf(-dv[2 * kl + (jj >> 2)][jj & 3] * inv_ht);
          s0 += w;
          wf[jj] = (short)f2bf(w);
        }
        accR = MFMA(wf, xbs[kl], accR);
      }
      s0 += __shfl_xor(s0, 16);
      s0 += __shfl_xor(s0, 32);
      float* combS = sf;           // [3][64][4]
      float* combR = sf + 768;
      float* sc_s = sf + 1536;     // [16][16]
      float* s1_s = sf + 1792;
      float* s0p  = sf + 2048;     // [16][4]
      if (wv) {
#pragma unroll
        for (int rg2 = 0; rg2 < 4; rg2++) {
          combS[((wv - 1) * 64 + lane) * 4 + rg2] = accS[rg2];
          combR[((wv - 1) * 64 + lane) * 4 + rg2] = accR[rg2];
        }
      }
      if (q == 0) s0p[m * 4 + wv] = s0;
      __syncthreads();
      if (wv == 0) {
        float ob = out_b[uc0 + m];
#pragma unroll
        for (int rg2 = 0; rg2 < 4; rg2++) {
          float aS = accS[rg2], aR = accR[rg2];
#pragma unroll
          for (int w2 = 0; w2 < 3; w2++) {
            aS += combS[(w2 * 64 + lane) * 4 + rg2];
            aR += combR[(w2 * 64 + lane) * 4 + rg2];
          }
          sc_s[(q * 4 + rg2) * 16 + m] = aS + ob;
          s1_s[(q * 4 + rg2) * 16 + m] = aR;
        }
      }
      __syncthreads();
      float* comp = sf;        // [16][8] (combS dead)
      float* w8   = sf + 128;  // [16][8]
      float* wm   = sf + 256;  // [16][16]
      if (tid < 128) {
        int r = tid >> 3, mm = tid & 7;
        const float* xr = xold + r * 64;
        const float* mr = mu + mm * 64;
        float s = 0.f;
#pragma unroll 8
        for (int d = 0; d < 64; d++) { float df = xr[d] - mr[d]; s = fmaf(df, df, s); }
        comp[r * 8 + mm] = -0.5f * s;
      }
      __syncthreads();
      if (tid < 16) {
        float mx = comp[tid * 8];
        for (int j2 = 1; j2 < 8; j2++) mx = fmaxf(mx, comp[tid * 8 + j2]);
        float sm = 0.f; float e[8];
        for (int j2 = 0; j2 < 8; j2++) { e[j2] = __expf(comp[tid * 8 + j2] - mx); sm += e[j2]; }
        float inv = 1.0f / sm;
        for (int j2 = 0; j2 < 8; j2++) w8[tid * 8 + j2] = e[j2] * inv;
      }
      __syncthreads();
      {
        int r = tid >> 4, dl = tid & 15;
        float a2 = 0.f;
#pragma unroll
        for (int mm = 0; mm < 8; mm++) a2 = fmaf(w8[r * 8 + mm], mu[mm * 64 + uc0 + dl], a2);
        wm[r * 16 + dl] = a2;
      }
      __syncthreads();
      {
        float tb = BET[step];
        float dt = eps[0];
        float sq = sqrtf(2.0f * dt);
        int r = tid >> 4, dl = tid & 15;
        int grow = ur0 + r, d = uc0 + dl;
        float s0r = s0p[r * 4] + s0p[r * 4 + 1] + s0p[r * 4 + 2] + s0p[r * 4 + 3];
        float cR = -0.1f * inv_ht;
        float xv = xold[r * 64 + d];
        float g = -xv + tb * wm[r * 16 + dl];                // grad log pi
        float rep = cR * (xv * s0r - s1_s[r * 16 + dl]);     // repel(x_old)
        float nv = xv + dt * (g - sc_s[r * 16 + dl]) - dt * rep + sq * noise_i[grow * 64 + d];
        scst_f32(x_new + grow * 64 + d, nv);
        u16 bv = f2bf(nv);
        scst_u16(xbf + grow * 64 + d, bv);
        scst_u16(xT_out + d * 512 + grow, bv);
      }
    } else {
      // zero other-parity hists for next step
      int bb = b - 128;
      u32* hcO = (u32*)(ws + WS_COARSE) + (p ^ 1) * 2048;
      u32* hfO = (u32*)(ws + WS_FINE) + (p ^ 1) * 2048;
      if (tid < 32) {
        int w = bb * 32 + tid;
        if (w < 2048) scst_u32(&hcO[w], 0u); else scst_u32(&hfO[w - 2048], 0u);
      }
    }
    gsync(bar, 256u * (++rnd), false);
  }
}

extern "C" void kernel_launch(void* const* d_in, const int* in_sizes, int n_in,
                              void* d_out, int out_size, void* d_ws, size_t ws_size,
                              hipStream_t stream) {
  (void)in_sizes; (void)n_in; (void)out_size; (void)ws_size;
  const float* particles    = (const float*)d_in[0];
  const float* noises       = (const float*)d_in[1];
  const float* grid_t       = (const float*)d_in[2];
  const float* eps          = (const float*)d_in[3];
  const float* target_means = (const float*)d_in[4];
  const float* phase        = (const float*)d_in[5];
  const float* in_W         = (const float*)d_in[6];
  const float* in_b         = (const float*)d_in[7];
  const float* t_W1         = (const float*)d_in[8];
  const float* t_b1         = (const float*)d_in[9];
  const float* t_W2         = (const float*)d_in[10];
  const float* t_b2         = (const float*)d_in[11];
  const float* h_W          = (const float*)d_in[12];
  const float* h_b          = (const float*)d_in[13];
  const float* out_W        = (const float*)d_in[14];
  const float* out_b        = (const float*)d_in[15];
  float* traj = (float*)d_out;
  char* ws = (char*)d_ws;

  hipMemsetAsync(ws + WS_BAR, 0, 64, stream);

  void* args[] = {
    (void*)&particles, (void*)&noises, (void*)&grid_t, (void*)&eps,
    (void*)&target_means, (void*)&phase, (void*)&in_W, (void*)&in_b,
    (void*)&t_W1, (void*)&t_b1, (void*)&t_W2, (void*)&t_b2,
    (void*)&h_W, (void*)&h_b, (void*)&out_W, (void*)&out_b,
    (void*)&traj, (void*)&ws
  };
  hipLaunchCooperativeKernel((void*)mega, dim3(256), dim3(256), args, 0, stream);
}

// Round 6
// 424.697 us; speedup vs baseline: 3.5908x; 1.4384x over previous
//
#include <hip/hip_runtime.h>
#include <math.h>

// CMCD sampler: persistent cooperative kernel, 256 blocks x 256 threads.
// R6: hierarchical sync. Layer deps are row-group-local (8 blocks share rg):
// local barriers on per-rg cachelines. Cross-rg x-propagation via per-rg epoch
// flags (gram polls only its 5 producer rgs). Histogram sync is split-phase
// with per-rg replicated arrival counters (arrive P1/P3, wait P3/P5 — hidden).
// 4-deep hist rotation + SD step counter handle pipeline skew. sc0sc1 for all
// cross-block mutable data; plain cached loads for immutable weights.

typedef __attribute__((ext_vector_type(8))) short short8;
typedef __attribute__((ext_vector_type(4))) float floatx4;
typedef __attribute__((ext_vector_type(2))) unsigned int u32x2;
typedef unsigned int u32;
typedef unsigned short u16;

// ---- workspace byte offsets (~4.09 MB) ----
#define WS_RGCNT   0u         // u32[32] stride 32 words (128B lines) local arrivals
#define WS_RGDONE  4096u      // u32[32] stride 32: steps completed per rg
#define WS_RGREL   8192u      // u32[32] stride 32: prep global release epoch
#define WS_HCNT    12288u     // u32[32] stride 32: coarse-hist arrivals per rg
#define WS_HFNT    16384u     // u32[32] stride 32: fine-hist arrivals per rg
#define WS_GC      20480u     // u32 prep global counter
#define WS_SD      20608u     // u32 rg-step-done counter
#define WS_BETAS   20736u     // f32[16]
// memset 0..24576 each launch
#define WS_COARSE  24576u     // u32[4 set][4 rep][512]
#define WS_FINE    57344u     // u32[4 set][4 rep][512]
#define WS_TEP     90112u     // f32[4*8*512]
#define WS_G1P     155648u    // f32[8*8*512]
#define WS_XBF     286720u    // u16[512*64]
#define WS_XBFT0   352256u    // u16[64*512]
#define WS_XBFT1   417792u    // u16[64*512]
#define WS_INWT    483328u    // u16[512*64]
#define WS_OUTWT   548864u    // u16[64*512]
#define WS_HWT     614400u    // u16[3*512*512]
#define WS_D2      2187264u   // f32[512*512]
#define WS_H0      3235840u   // u16[512*512]
#define WS_H1      3760128u   // u16[512*512]

__device__ __forceinline__ u16 f2bf(float f) {
  u32 u = __float_as_uint(f);
  u32 r = u + 0x7FFFu + ((u >> 16) & 1u);
  return (u16)(r >> 16);
}
__device__ __forceinline__ float bf2f(u16 v) {
  return __uint_as_float(((u32)v) << 16);
}

// tanh-approx gelu (jax.nn.gelu default approximate=True)
__device__ __forceinline__ float gelu_f(float x) {
  float y = 0.7978845608028654f * (x + 0.044715f * x * x * x);
  float ay = fabsf(y);
  float e = __expf(-2.0f * ay);
  float t = (1.0f - e) / (1.0f + e);
  t = (y < 0.0f) ? -t : t;
  return 0.5f * x * (1.0f + t);
}

// ======================= sc0 sc1 (system-scope) access ======================
__device__ __forceinline__ u32 scld_u32(const u32* p) {
  u32 r;
  asm volatile("global_load_dword %0, %1, off sc0 sc1\n\ts_waitcnt vmcnt(0)"
               : "=v"(r) : "v"(p) : "memory");
  return r;
}
__device__ __forceinline__ void scld_f4(const float* p, floatx4& r) {
  asm volatile("global_load_dwordx4 %0, %1, off sc0 sc1\n\ts_waitcnt vmcnt(0)"
               : "=v"(r) : "v"(p) : "memory");
}
__device__ __forceinline__ void scld_gram(const u16* pa, const u16* pb,
                                          short8& a0, short8& a1, short8& b0, short8& b1) {
  asm volatile(
    "global_load_dwordx4 %0, %4, off sc0 sc1\n\t"
    "global_load_dwordx4 %1, %4, off offset:64 sc0 sc1\n\t"
    "global_load_dwordx4 %2, %5, off sc0 sc1\n\t"
    "global_load_dwordx4 %3, %5, off offset:64 sc0 sc1\n\t"
    "s_waitcnt vmcnt(0)"
    : "=&v"(a0), "=&v"(a1), "=&v"(b0), "=&v"(b1)
    : "v"(pa), "v"(pb) : "memory");
}
__device__ __forceinline__ void scld16_64(const u16* p, short8* a) {
  asm volatile(
    "global_load_dwordx4 %0, %16, off sc0 sc1\n\t"
    "global_load_dwordx4 %1, %16, off offset:64 sc0 sc1\n\t"
    "global_load_dwordx4 %2, %16, off offset:128 sc0 sc1\n\t"
    "global_load_dwordx4 %3, %16, off offset:192 sc0 sc1\n\t"
    "global_load_dwordx4 %4, %16, off offset:256 sc0 sc1\n\t"
    "global_load_dwordx4 %5, %16, off offset:320 sc0 sc1\n\t"
    "global_load_dwordx4 %6, %16, off offset:384 sc0 sc1\n\t"
    "global_load_dwordx4 %7, %16, off offset:448 sc0 sc1\n\t"
    "global_load_dwordx4 %8, %16, off offset:512 sc0 sc1\n\t"
    "global_load_dwordx4 %9, %16, off offset:576 sc0 sc1\n\t"
    "global_load_dwordx4 %10, %16, off offset:640 sc0 sc1\n\t"
    "global_load_dwordx4 %11, %16, off offset:704 sc0 sc1\n\t"
    "global_load_dwordx4 %12, %16, off offset:768 sc0 sc1\n\t"
    "global_load_dwordx4 %13, %16, off offset:832 sc0 sc1\n\t"
    "global_load_dwordx4 %14, %16, off offset:896 sc0 sc1\n\t"
    "global_load_dwordx4 %15, %16, off offset:960 sc0 sc1\n\t"
    "s_waitcnt vmcnt(0)"
    : "=&v"(a[0]), "=&v"(a[1]), "=&v"(a[2]), "=&v"(a[3]),
      "=&v"(a[4]), "=&v"(a[5]), "=&v"(a[6]), "=&v"(a[7]),
      "=&v"(a[8]), "=&v"(a[9]), "=&v"(a[10]), "=&v"(a[11]),
      "=&v"(a[12]), "=&v"(a[13]), "=&v"(a[14]), "=&v"(a[15])
    : "v"(p) : "memory");
}
__device__ __forceinline__ void scld4_64(const u16* p, short8& r0, short8& r1,
                                         short8& r2, short8& r3) {
  asm volatile(
    "global_load_dwordx4 %0, %4, off sc0 sc1\n\t"
    "global_load_dwordx4 %1, %4, off offset:64 sc0 sc1\n\t"
    "global_load_dwordx4 %2, %4, off offset:128 sc0 sc1\n\t"
    "global_load_dwordx4 %3, %4, off offset:192 sc0 sc1\n\t"
    "s_waitcnt vmcnt(0)"
    : "=&v"(r0), "=&v"(r1), "=&v"(r2), "=&v"(r3)
    : "v"(p) : "memory");
}
__device__ __forceinline__ void scld8_d2(const float* p, floatx4* d) {
  asm volatile(
    "global_load_dwordx4 %0, %8, off sc0 sc1\n\t"
    "global_load_dwordx4 %1, %8, off offset:16 sc0 sc1\n\t"
    "global_load_dwordx4 %2, %8, off offset:128 sc0 sc1\n\t"
    "global_load_dwordx4 %3, %8, off offset:144 sc0 sc1\n\t"
    "global_load_dwordx4 %4, %8, off offset:256 sc0 sc1\n\t"
    "global_load_dwordx4 %5, %8, off offset:272 sc0 sc1\n\t"
    "global_load_dwordx4 %6, %8, off offset:384 sc0 sc1\n\t"
    "global_load_dwordx4 %7, %8, off offset:400 sc0 sc1\n\t"
    "s_waitcnt vmcnt(0)"
    : "=&v"(d[0]), "=&v"(d[1]), "=&v"(d[2]), "=&v"(d[3]),
      "=&v"(d[4]), "=&v"(d[5]), "=&v"(d[6]), "=&v"(d[7])
    : "v"(p) : "memory");
}
__device__ __forceinline__ void scld4_u2(const u32* p0, const u32* p1,
                                         const u32* p2, const u32* p3,
                                         u32x2& r0, u32x2& r1, u32x2& r2, u32x2& r3) {
  asm volatile(
    "global_load_dwordx2 %0, %4, off sc0 sc1\n\t"
    "global_load_dwordx2 %1, %5, off sc0 sc1\n\t"
    "global_load_dwordx2 %2, %6, off sc0 sc1\n\t"
    "global_load_dwordx2 %3, %7, off sc0 sc1\n\t"
    "s_waitcnt vmcnt(0)"
    : "=&v"(r0), "=&v"(r1), "=&v"(r2), "=&v"(r3)
    : "v"(p0), "v"(p1), "v"(p2), "v"(p3) : "memory");
}
__device__ __forceinline__ void scst_f32(float* p, float v) {
  asm volatile("global_store_dword %0, %1, off sc0 sc1" :: "v"(p), "v"(v) : "memory");
}
__device__ __forceinline__ void scst_u32(u32* p, u32 v) {
  asm volatile("global_store_dword %0, %1, off sc0 sc1" :: "v"(p), "v"(v) : "memory");
}
__device__ __forceinline__ void scst_u16(u16* p, u16 v) {
  u32 x = v;
  asm volatile("global_store_short %0, %1, off sc0 sc1" :: "v"(p), "v"(x) : "memory");
}

#define MFMA(a, b, c) __builtin_amdgcn_mfma_f32_16x16x32_bf16((a), (b), (c), 0, 0, 0)

__global__ __launch_bounds__(256) void mega(
    const float* __restrict__ particles, const float* __restrict__ noises,
    const float* __restrict__ grid_t, const float* __restrict__ eps,
    const float* __restrict__ mu, const float* __restrict__ phase,
    const float* __restrict__ in_W, const float* __restrict__ in_b,
    const float* __restrict__ t_W1, const float* __restrict__ t_b1,
    const float* __restrict__ t_W2, const float* __restrict__ t_b2,
    const float* __restrict__ h_W, const float* __restrict__ h_b,
    const float* __restrict__ out_W, const float* __restrict__ out_b,
    float* __restrict__ traj, char* __restrict__ ws)
{
  __shared__ u32 su[512];
  __shared__ float sf[3200];
  __shared__ float medf[4];
  __shared__ float rn_s[16];

  u32* rgcnt = (u32*)(ws + WS_RGCNT);
  u32* rgdone = (u32*)(ws + WS_RGDONE);
  u32* rgrel = (u32*)(ws + WS_RGREL);
  u32* hcnt = (u32*)(ws + WS_HCNT);
  u32* hfnt = (u32*)(ws + WS_HFNT);
  u32* GC = (u32*)(ws + WS_GC);
  u32* SD = (u32*)(ws + WS_SD);
  float* BET = (float*)(ws + WS_BETAS);
  u32* coarse = (u32*)(ws + WS_COARSE);
  u32* fine = (u32*)(ws + WS_FINE);
  float* TEP = (float*)(ws + WS_TEP);
  float* G1P = (float*)(ws + WS_G1P);
  u16* xbf = (u16*)(ws + WS_XBF);
  u16* inWT = (u16*)(ws + WS_INWT);
  u16* outWT = (u16*)(ws + WS_OUTWT);
  u16* hWT = (u16*)(ws + WS_HWT);
  float* d2g = (float*)(ws + WS_D2);
  u16* h0g = (u16*)(ws + WS_H0);
  u16* h1g = (u16*)(ws + WS_H1);

  const int b = blockIdx.x;
  const int tid = threadIdx.x;
  const int wv = tid >> 6, lane = tid & 63;
  const int m = lane & 15, q = lane >> 4;
  const int rg = b >> 3, cg = b & 7;
  u32 lrnd = 0, grnd = 0;

  // local sync macro pattern (extra = additional per-rg arrival counter or null)
#define LSYNC(extra_ptr)                                                        \
  do {                                                                          \
    lrnd++;                                                                     \
    asm volatile("s_waitcnt vmcnt(0)" ::: "memory");                            \
    __syncthreads();                                                            \
    if (tid == 0) {                                                             \
      u32* _e = (extra_ptr);                                                    \
      if (_e) __hip_atomic_fetch_add(_e, 1u, __ATOMIC_RELAXED, __HIP_MEMORY_SCOPE_AGENT); \
      __hip_atomic_fetch_add(&rgcnt[rg * 32], 1u, __ATOMIC_RELAXED, __HIP_MEMORY_SCOPE_AGENT); \
      while (scld_u32(&rgcnt[rg * 32]) < 8u * lrnd) __builtin_amdgcn_s_sleep(2); \
    }                                                                           \
    __syncthreads();                                                            \
  } while (0)

#define GBAR_HEAVY()                                                            \
  do {                                                                          \
    lrnd++; grnd++;                                                             \
    asm volatile("s_waitcnt vmcnt(0)" ::: "memory");                            \
    __syncthreads();                                                            \
    if (tid == 0) {                                                             \
      __threadfence();                                                          \
      __hip_atomic_fetch_add(&rgcnt[rg * 32], 1u, __ATOMIC_RELAXED, __HIP_MEMORY_SCOPE_AGENT); \
      if (cg == 0) {                                                            \
        while (scld_u32(&rgcnt[rg * 32]) < 8u * lrnd) __builtin_amdgcn_s_sleep(8); \
        __hip_atomic_fetch_add(GC, 1u, __ATOMIC_RELAXED, __HIP_MEMORY_SCOPE_AGENT); \
        while (scld_u32(GC) < 32u * grnd) __builtin_amdgcn_s_sleep(8);          \
        scst_u32(&rgrel[rg * 32], grnd);                                        \
      } else {                                                                  \
        while (scld_u32(&rgrel[rg * 32]) < grnd) __builtin_amdgcn_s_sleep(8);   \
      }                                                                         \
      __threadfence();                                                          \
    }                                                                           \
    __syncthreads();                                                            \
  } while (0)

  // ================= P0: prep jobs (plain stores; heavy-synced) =============
  for (int j = b; j < 916; j += 256) {
    if (j < 64) {                      // t-MLP pre-act partial, K-chain 128
      int slice = j >> 3, ii = j & 7;
      float* temb = sf;
      if (tid < 128) {
        int kglob = slice * 128 + tid;
        int kc = kglob & 511;
        float cf = 0.1f + (float)kc * (99.9f / 511.0f);
        float e = cf * (float)ii + phase[kc];
        temb[tid] = (kglob < 512) ? sinf(e) : cosf(e);
      }
      __syncthreads();
      for (int h = 0; h < 2; h++) {
        int c = h * 256 + tid;
        float acc = (slice == 0) ? t_b1[c] : 0.0f;
        const float* wp = t_W1 + (u32)(slice * 128) * 512u + c;
#pragma unroll 8
        for (int kk = 0; kk < 128; kk++) acc = fmaf(temb[kk], wp[kk * 512], acc);
        G1P[(slice * 8 + ii) * 512 + c] = acc;
      }
    } else if (j < 896) {              // LDS-tiled weight transposes -> bf16
      float* tile = sf;                // [32][33]
      int tx = tid & 31, ty0 = tid >> 5;
      const float* src; u16* dst; int sstr, dstr;
      if (j < 832) {
        int ti = j - 64; int l = ti >> 8, rem = ti & 255, kt = rem >> 4, ct = rem & 15;
        src = h_W + l * 262144 + kt * 32 * 512 + ct * 32; sstr = 512;
        dst = hWT + l * 262144 + ct * 32 * 512 + kt * 32; dstr = 512;
      } else if (j < 864) {
        int ti = j - 832; int kt = ti >> 4, ct = ti & 15;
        src = in_W + kt * 32 * 512 + ct * 32; sstr = 512;
        dst = inWT + ct * 32 * 64 + kt * 32; dstr = 64;
      } else {
        int ti = j - 864; int ct = ti >> 4, kt = ti & 15;
        src = out_W + kt * 32 * 64 + ct * 32; sstr = 64;
        dst = outWT + ct * 32 * 512 + kt * 32; dstr = 512;
      }
#pragma unroll
      for (int r = 0; r < 4; r++) { int ty = ty0 + r * 8; tile[ty * 33 + tx] = src[ty * sstr + tx]; }
      __syncthreads();
#pragma unroll
      for (int r = 0; r < 4; r++) { int ty = ty0 + r * 8; dst[ty * dstr + tx] = f2bf(tile[tx * 33 + ty]); }
    } else if (j < 912) {              // x copies: traj row0, xbf, xbfT0
      int jj = j - 896;
      u16* xbfT0 = (u16*)(ws + WS_XBFT0);
#pragma unroll
      for (int k2 = 0; k2 < 8; k2++) {
        u32 e = (u32)jj * 2048u + (u32)(k2 * 256) + (u32)tid;
        float v = particles[e];
        traj[e] = v;
        u16 bv = f2bf(v);
        xbf[e] = bv;
        xbfT0[(e & 63u) * 512u + (e >> 6)] = bv;
      }
    } else {                           // hist zero (all 4 sets) + betas
      u32 base = (u32)(j - 912) * 4096u;
      for (int k2 = 0; k2 < 16; k2++) {
        u32 w = base + (u32)(k2 * 256) + (u32)tid;
        if (w < 8192u) coarse[w] = 0u; else fine[w - 8192u] = 0u;
      }
      if (j == 912 && tid == 0) {
        float sig[8]; float tot = 0.f;
        for (int k2 = 0; k2 < 8; k2++) { sig[k2] = 1.0f / (1.0f + __expf(-grid_t[k2])); tot += sig[k2]; }
        float cum = 0.f; BET[0] = 0.f;
        for (int k2 = 0; k2 < 8; k2++) { cum += sig[k2]; BET[k2 + 1] = cum / tot; }
      }
    }
    __syncthreads();
  }
  GBAR_HEAVY();

  // ================= P0b: te partial slabs (32 jobs) =========================
  if (b < 32) {
    int ii = b >> 2, kq = b & 3;
    float* g1 = sf;
    if (tid < 128) {
      int kglob = kq * 128 + tid;
      float s = 0.f;
#pragma unroll
      for (int sl = 0; sl < 8; sl++) s += G1P[(sl * 8 + ii) * 512 + kglob];
      g1[tid] = gelu_f(s);
    }
    __syncthreads();
    for (int h = 0; h < 2; h++) {
      int c = h * 256 + tid;
      float acc = (kq == 0) ? (t_b2[c] + in_b[c]) : 0.0f;
      const float* wp = t_W2 + (u32)(kq * 128) * 512u + c;
#pragma unroll 8
      for (int kk = 0; kk < 128; kk++) acc = fmaf(g1[kk], wp[kk * 512], acc);
      TEP[(kq * 8 + ii) * 512 + c] = acc;
    }
  }
  GBAR_HEAVY();   // after this, weights/TEP/BET are immutable & cacheable

  // ================= main loop ==============================================
  const int r0 = rg * 16;
  const int cA = cg * 64;

  for (int step = 0; step < 8; step++) {
    const int hs = step & 3;
    u32* corP = coarse + hs * 2048;
    u32* finP = fine + hs * 2048;
    const u16* xT_in = (const u16*)(ws + ((step & 1) ? WS_XBFT1 : WS_XBFT0));
    u16* xT_out = (u16*)(ws + ((step & 1) ? WS_XBFT0 : WS_XBFT1));
    const float* x_old = traj + step * 32768;
    float* x_new = traj + (step + 1) * 32768;
    const float* noise_i = noises + step * 32768;

    // -------- P1: flag-wait, gram + coarse hist + L0 ------------------------
    if (tid < 5) {
      int need = (tid < 4) ? (4 * cg + tid) : rg;
      while (scld_u32(&rgdone[need * 32]) < (u32)step) __builtin_amdgcn_s_sleep(2);
    }
    __syncthreads();
    floatx4 d2r;
    {
      int c0 = cA + wv * 16;
      short8 a0, a1, b0, b1;
      scld_gram(xbf + (r0 + m) * 64 + q * 8, xbf + (c0 + m) * 64 + q * 8, a0, a1, b0, b1);
      float rp = 0.f, cp = 0.f;
#pragma unroll
      for (int jj = 0; jj < 8; jj++) {
        float v;
        v = bf2f((u16)a0[jj]); rp = fmaf(v, v, rp);
        v = bf2f((u16)a1[jj]); rp = fmaf(v, v, rp);
        v = bf2f((u16)b0[jj]); cp = fmaf(v, v, cp);
        v = bf2f((u16)b1[jj]); cp = fmaf(v, v, cp);
      }
      rp += __shfl_xor(rp, 16); rp += __shfl_xor(rp, 32);
      cp += __shfl_xor(cp, 16); cp += __shfl_xor(cp, 32);
      if (wv == 0 && q == 0) rn_s[m] = rp;
      su[tid] = 0u; su[256 + tid] = 0u;
      __syncthreads();
      floatx4 acc = {0.f, 0.f, 0.f, 0.f};
      acc = MFMA(a0, b0, acc);
      acc = MFMA(a1, b1, acc);
#pragma unroll
      for (int rg2 = 0; rg2 < 4; rg2++) {
        int rl = q * 4 + rg2;
        float v = rn_s[rl] + cp - 2.0f * acc[rg2];
        d2r[rg2] = v;
        scst_f32(d2g + (r0 + rl) * 512 + c0 + m, v);
        int bin = (int)(v * 0.5f);
        bin = bin < 0 ? 0 : (bin > 511 ? 511 : bin);
        atomicAdd(&su[bin], 1u);
      }
      __syncthreads();
      u32 rep = (u32)(b & 3) * 512u;
      u32 v0 = su[tid]; if (v0) atomicAdd(&corP[rep + tid], v0);
      u32 v1 = su[256 + tid]; if (v1) atomicAdd(&corP[rep + 256 + tid], v1);
      // L0
      short8 w0 = *(const short8*)(inWT + (c0 + m) * 64 + q * 8);
      short8 w1 = *(const short8*)(inWT + (c0 + m) * 64 + 32 + q * 8);
      floatx4 fac = {0.f, 0.f, 0.f, 0.f};
      fac = MFMA(a0, w0, fac);
      fac = MFMA(a1, w1, fac);
      int col = c0 + m;
      float bv = TEP[step * 512 + col] + TEP[4096 + step * 512 + col]
               + TEP[8192 + step * 512 + col] + TEP[12288 + step * 512 + col];
#pragma unroll
      for (int rg2 = 0; rg2 < 4; rg2++)
        scst_u16(h0g + (r0 + q * 4 + rg2) * 512 + col, f2bf(gelu_f(fac[rg2] + bv)));
    }
    LSYNC(&hcnt[rg * 32]);

    // -------- P2: L1 --------------------------------------------------------
    {
      int c0 = cA + wv * 16;
      short8 a[16];
      scld16_64(h0g + (r0 + m) * 512 + q * 8, a);
      floatx4 acc = {0.f, 0.f, 0.f, 0.f};
#pragma unroll
      for (int kk = 0; kk < 16; kk++) {
        short8 bb = *(const short8*)(hWT + (c0 + m) * 512 + kk * 32 + q * 8);
        acc = MFMA(a[kk], bb, acc);
      }
      int col = c0 + m;
      float bv = h_b[col];
#pragma unroll
      for (int rg2 = 0; rg2 < 4; rg2++)
        scst_u16(h1g + (r0 + q * 4 + rg2) * 512 + col, f2bf(gelu_f(acc[rg2] + bv)));
    }
    LSYNC((u32*)0);

    // -------- P3: L2 + coarse scan + fine contrib ---------------------------
    u32 base0; float lo2, invbw, binw;
    {
      int c0 = cA + wv * 16;
      short8 a[16];
      scld16_64(h1g + (r0 + m) * 512 + q * 8, a);
      floatx4 acc = {0.f, 0.f, 0.f, 0.f};
#pragma unroll
      for (int kk = 0; kk < 16; kk++) {
        short8 bb = *(const short8*)(hWT + 262144 + (c0 + m) * 512 + kk * 32 + q * 8);
        acc = MFMA(a[kk], bb, acc);
      }
      int col = c0 + m;
      float bv = h_b[512 + col];
#pragma unroll
      for (int rg2 = 0; rg2 < 4; rg2++)
        scst_u16(h0g + (r0 + q * 4 + rg2) * 512 + col, f2bf(gelu_f(acc[rg2] + bv)));

      // wait: all coarse-hist arrivals (per-rg lines; hidden by 2-phase lag)
      if (tid < 32) {
        while (scld_u32(&hcnt[tid * 32]) < 8u * (u32)(step + 1)) __builtin_amdgcn_s_sleep(2);
      }
      __syncthreads();
      // coarse scan (pairs: thread t handles bins 2t, 2t+1)
      u32x2 h0p, h1p, h2p, h3p;
      scld4_u2(&corP[2 * tid], &corP[512 + 2 * tid], &corP[1024 + 2 * tid], &corP[1536 + 2 * tid],
               h0p, h1p, h2p, h3p);
      u32 c0c = h0p.x + h1p.x + h2p.x + h3p.x;
      u32 c1c = h0p.y + h1p.y + h2p.y + h3p.y;
      su[tid] = c0c + c1c;
      __syncthreads();
      for (int off = 1; off < 256; off <<= 1) {
        u32 add = (tid >= off) ? su[tid - off] : 0u;
        __syncthreads(); su[tid] += add; __syncthreads();
      }
      u32 incl = su[tid], excl = incl - c0c - c1c;
#pragma unroll
      for (int tr = 0; tr < 2; tr++) {
        u32 R = 131071u + (u32)tr;
        if (R >= excl && R < excl + c0c) { su[300 + tr] = 2u * tid; if (tr == 0) su[304] = excl; }
        else if (R >= excl + c0c && R < incl) { su[300 + tr] = 2u * tid + 1u; if (tr == 0) su[304] = excl + c0c; }
      }
      __syncthreads();
      u32 cb0 = su[300], cb1 = su[301];
      base0 = su[304];
      lo2 = (float)cb0 * 2.0f;
      float width = (float)(cb1 - cb0 + 1u) * 2.0f;
      invbw = 512.0f / width;
      binw = width * (1.0f / 512.0f);
      __syncthreads();
      su[tid] = 0u; su[256 + tid] = 0u;
      __syncthreads();
#pragma unroll
      for (int rg2 = 0; rg2 < 4; rg2++) {
        float v = d2r[rg2];
        int cbv = (int)(v * 0.5f); cbv = cbv < 0 ? 0 : (cbv > 511 ? 511 : cbv);
        if ((u32)cbv >= cb0 && (u32)cbv <= cb1) {
          int fb = (int)((v - lo2) * invbw);
          fb = fb < 0 ? 0 : (fb > 511 ? 511 : fb);
          atomicAdd(&su[fb], 1u);
        }
      }
      __syncthreads();
      u32 rep = (u32)(b & 3) * 512u;
      u32 v0 = su[tid]; if (v0) atomicAdd(&finP[rep + tid], v0);
      u32 v1 = su[256 + tid]; if (v1) atomicAdd(&finP[rep + 256 + tid], v1);
    }
    LSYNC(&hfnt[rg * 32]);

    // -------- P4: L3 --------------------------------------------------------
    {
      int c0 = cA + wv * 16;
      short8 a[16];
      scld16_64(h0g + (r0 + m) * 512 + q * 8, a);
      floatx4 acc = {0.f, 0.f, 0.f, 0.f};
#pragma unroll
      for (int kk = 0; kk < 16; kk++) {
        short8 bb = *(const short8*)(hWT + 524288 + (c0 + m) * 512 + kk * 32 + q * 8);
        acc = MFMA(a[kk], bb, acc);
      }
      int col = c0 + m;
      float bv = h_b[1024 + col];
#pragma unroll
      for (int rg2 = 0; rg2 < 4; rg2++)
        scst_u16(h1g + (r0 + q * 4 + rg2) * 512 + col, f2bf(gelu_f(acc[rg2] + bv)));
    }
    LSYNC((u32*)0);

    // -------- P5: update (cg<4) / hist-zero (cg>=4) -------------------------
    if (tid < 32) {
      while (scld_u32(&hfnt[tid * 32]) < 8u * (u32)(step + 1)) __builtin_amdgcn_s_sleep(2);
    }
    if (tid == 32) {
      while (scld_u32(SD) < 32u * (u32)step) __builtin_amdgcn_s_sleep(2);
    }
    __syncthreads();
    if (cg < 4) {
      const int uc0 = cg * 16;
      // stage x_old rows into LDS
      float* xold = sf + 2112;   // [16][64]
      {
        int r = tid >> 4, c4 = tid & 15;
        floatx4 xv4;
        scld_f4(x_old + (r0 + r) * 64 + c4 * 4, xv4);
        *(floatx4*)(xold + r * 64 + c4 * 4) = xv4;
      }
      // fine median select
      {
        u32x2 f0p, f1p, f2p, f3p;
        scld4_u2(&finP[2 * tid], &finP[512 + 2 * tid], &finP[1024 + 2 * tid], &finP[1536 + 2 * tid],
                 f0p, f1p, f2p, f3p);
        u32 f0 = f0p.x + f1p.x + f2p.x + f3p.x;
        u32 f1 = f0p.y + f1p.y + f2p.y + f3p.y;
        su[tid] = f0 + f1;
        __syncthreads();
        for (int off = 1; off < 256; off <<= 1) {
          u32 add = (tid >= off) ? su[tid - off] : 0u;
          __syncthreads(); su[tid] += add; __syncthreads();
        }
        u32 incl = su[tid], excl = incl - f0 - f1;
#pragma unroll
        for (int tr = 0; tr < 2; tr++) {
          u32 rl = 131071u + (u32)tr - base0;
          u32 fb = 0, flo = 0, cnt = 0; bool hit = false;
          if (rl >= excl && rl < excl + f0) { fb = 2u * tid; flo = excl; cnt = f0; hit = true; }
          else if (rl >= excl + f0 && rl < incl) { fb = 2u * tid + 1u; flo = excl + f0; cnt = f1; hit = true; }
          if (hit) {
            float d2v = lo2 + ((float)fb + ((float)(rl - flo) + 0.5f) / (float)cnt) * binw;
            medf[tr] = sqrtf(fmaxf(d2v, 1e-12f));
          }
        }
        __syncthreads();
        if (tid == 0) {
          float md = 0.5f * (medf[0] + medf[1]);
          medf[2] = 6.2383246250395075f / (md * md);   // log(512)/h_t
        }
        __syncthreads();
      }
      float inv_ht = medf[2];
      // score + S1 GEMMs, wave wv = K-slice of 4 kk
      short8 ha0, ha1, ha2, ha3, xb0, xb1, xb2, xb3;
      scld4_64(h1g + (r0 + m) * 512 + wv * 128 + q * 8, ha0, ha1, ha2, ha3);
      scld4_64(xT_in + (uc0 + m) * 512 + wv * 128 + q * 8, xb0, xb1, xb2, xb3);
      floatx4 dv[8];
      scld8_d2(d2g + (r0 + m) * 512 + wv * 128 + q * 8, dv);
      floatx4 accS = {0.f, 0.f, 0.f, 0.f}, accR = {0.f, 0.f, 0.f, 0.f};
      float s0 = 0.f;
      short8 has[4] = {ha0, ha1, ha2, ha3};
      short8 xbs[4] = {xb0, xb1, xb2, xb3};
#pragma unroll
      for (int kl = 0; kl < 4; kl++) {
        int kk = wv * 4 + kl;
        short8 bw = *(const short8*)(outWT + (uc0 + m) * 512 + kk * 32 + q * 8);
        accS = MFMA(has[kl], bw, accS);
        short8 wf;
#pragma unroll
        for (int jj = 0; jj < 8; jj++) {
          float w = __expf(-dv[2 * kl + (jj >> 2)][jj & 3] * inv_ht);
          s0 += w;
          wf[jj] = (short)f2bf(w);
        }
        accR = MFMA(wf, xbs[kl], accR);
      }
      s0 += __shfl_xor(s0, 16);
      s0 += __shfl_xor(s0, 32);
      float* combS = sf;           // [3][64][4]
      float* combR = sf + 768;
      float* sc_s = sf + 1536;     // [16][16]
      float* s1_s = sf + 1792;
      float* s0p  = sf + 2048;     // [16][4]
      if (wv) {
#pragma unroll
        for (int rg2 = 0; rg2 < 4; rg2++) {
          combS[((wv - 1) * 64 + lane) * 4 + rg2] = accS[rg2];
          combR[((wv - 1) * 64 + lane) * 4 + rg2] = accR[rg2];
        }
      }
      if (q == 0) s0p[m * 4 + wv] = s0;
      __syncthreads();
      if (wv == 0) {
        float ob = out_b[uc0 + m];
#pragma unroll
        for (int rg2 = 0; rg2 < 4; rg2++) {
          float aS = accS[rg2], aR = accR[rg2];
#pragma unroll
          for (int w2 = 0; w2 < 3; w2++) {
            aS += combS[(w2 * 64 + lane) * 4 + rg2];
            aR += combR[(w2 * 64 + lane) * 4 + rg2];
          }
          sc_s[(q * 4 + rg2) * 16 + m] = aS + ob;
          s1_s[(q * 4 + rg2) * 16 + m] = aR;
        }
      }
      __syncthreads();
      float* comp = sf;        // [16][8] (combS dead)
      float* w8   = sf + 128;  // [16][8]
      float* wm   = sf + 256;  // [16][16]
      if (tid < 128) {
        int r = tid >> 3, mm = tid & 7;
        const float* xr = xold + r * 64;
        const float* mr = mu + mm * 64;
        float s = 0.f;
#pragma unroll 8
        for (int d = 0; d < 64; d++) { float df = xr[d] - mr[d]; s = fmaf(df, df, s); }
        comp[r * 8 + mm] = -0.5f * s;
      }
      __syncthreads();
      if (tid < 16) {
        float mx = comp[tid * 8];
        for (int j2 = 1; j2 < 8; j2++) mx = fmaxf(mx, comp[tid * 8 + j2]);
        float sm = 0.f; float e[8];
        for (int j2 = 0; j2 < 8; j2++) { e[j2] = __expf(comp[tid * 8 + j2] - mx); sm += e[j2]; }
        float inv = 1.0f / sm;
        for (int j2 = 0; j2 < 8; j2++) w8[tid * 8 + j2] = e[j2] * inv;
      }
      __syncthreads();
      {
        int r = tid >> 4, dl = tid & 15;
        float a2 = 0.f;
#pragma unroll
        for (int mm = 0; mm < 8; mm++) a2 = fmaf(w8[r * 8 + mm], mu[mm * 64 + uc0 + dl], a2);
        wm[r * 16 + dl] = a2;
      }
      __syncthreads();
      {
        float tb = BET[step];
        float dt = eps[0];
        float sq = sqrtf(2.0f * dt);
        int r = tid >> 4, dl = tid & 15;
        int grow = r0 + r, d = uc0 + dl;
        float s0r = s0p[r * 4] + s0p[r * 4 + 1] + s0p[r * 4 + 2] + s0p[r * 4 + 3];
        float cR = -0.1f * inv_ht;
        float xv = xold[r * 64 + d];
        float g = -xv + tb * wm[r * 16 + dl];                // grad log pi
        float rep = cR * (xv * s0r - s1_s[r * 16 + dl]);     // repel(x_old)
        float nv = xv + dt * (g - sc_s[r * 16 + dl]) - dt * rep + sq * noise_i[grow * 64 + d];
        scst_f32(x_new + grow * 64 + d, nv);
        u16 bv = f2bf(nv);
        scst_u16(xbf + grow * 64 + d, bv);
        scst_u16(xT_out + d * 512 + grow, bv);
      }
    } else {
      // zero hist set (step+2)%4 for reuse at step+2
      int zs = (step + 2) & 3;
      u32* zc = coarse + zs * 2048;
      u32* zf = fine + zs * 2048;
      int bb = rg * 4 + (cg - 4);   // 0..127
      if (tid < 16) {
        int w = bb * 16 + tid;
        scst_u32(&zc[w], 0u);
        scst_u32(&zf[w], 0u);
      }
    }
    LSYNC((u32*)0);
    if (tid == 0 && cg == 0) {
      __hip_atomic_fetch_add(SD, 1u, __ATOMIC_RELAXED, __HIP_MEMORY_SCOPE_AGENT);
      scst_u32(&rgdone[rg * 32], (u32)(step + 1));
    }
  }
#undef LSYNC
#undef GBAR_HEAVY
}

extern "C" void kernel_launch(void* const* d_in, const int* in_sizes, int n_in,
                              void* d_out, int out_size, void* d_ws, size_t ws_size,
                              hipStream_t stream) {
  (void)in_sizes; (void)n_in; (void)out_size; (void)ws_size;
  const float* particles    = (const float*)d_in[0];
  const float* noises       = (const float*)d_in[1];
  const float* grid_t       = (const float*)d_in[2];
  const float* eps          = (const float*)d_in[3];
  const float* target_means = (const float*)d_in[4];
  const float* phase        = (const float*)d_in[5];
  const float* in_W         = (const float*)d_in[6];
  const float* in_b         = (const float*)d_in[7];
  const float* t_W1         = (const float*)d_in[8];
  const float* t_b1         = (const float*)d_in[9];
  const float* t_W2         = (const float*)d_in[10];
  const float* t_b2         = (const float*)d_in[11];
  const float* h_W          = (const float*)d_in[12];
  const float* h_b          = (const float*)d_in[13];
  const float* out_W        = (const float*)d_in[14];
  const float* out_b        = (const float*)d_in[15];
  float* traj = (float*)d_out;
  char* ws = (char*)d_ws;

  hipMemsetAsync(ws, 0, 24576, stream);   // counters / flags / release words

  void* args[] = {
    (void*)&particles, (void*)&noises, (void*)&grid_t, (void*)&eps,
    (void*)&target_means, (void*)&phase, (void*)&in_W, (void*)&in_b,
    (void*)&t_W1, (void*)&t_b1, (void*)&t_W2, (void*)&t_b2,
    (void*)&h_W, (void*)&h_b, (void*)&out_W, (void*)&out_b,
    (void*)&traj, (void*)&ws
  };
  hipLaunchCooperativeKernel((void*)mega, dim3(256), dim3(256), args, 0, stream);
}

// Round 10
// 424.048 us; speedup vs baseline: 3.5963x; 1.0015x over previous
//
#include <hip/hip_runtime.h>
#include <math.h>

// CMCD sampler: persistent cooperative kernel, 256 blocks x 256 threads.
// R10 = R6 (proven passing structure, 424us) + micro-tweaks only:
//  - s_sleep lowered in spin loops (wake latency)
//  - P5's hfnt-all and SD polls merged into one divergence round
// Structure: hierarchical sync. Layer deps are row-group-local (8 blocks/rg):
// local barriers on per-rg cachelines. Cross-rg x-propagation via per-rg epoch
// flags. Histogram sync split-phase (arrive P1/P3, wait P3/P5). 4-deep hist
// rotation + SD step counter handle pipeline skew. sc0sc1 for all cross-block
// mutable data; plain cached loads for immutable weights.

typedef __attribute__((ext_vector_type(8))) short short8;
typedef __attribute__((ext_vector_type(4))) float floatx4;
typedef __attribute__((ext_vector_type(2))) unsigned int u32x2;
typedef unsigned int u32;
typedef unsigned short u16;

// ---- workspace byte offsets (~4.09 MB) ----
#define WS_RGCNT   0u         // u32[32] stride 32 words (128B lines) local arrivals
#define WS_RGDONE  4096u      // u32[32] stride 32: steps completed per rg
#define WS_RGREL   8192u      // u32[32] stride 32: prep global release epoch
#define WS_HCNT    12288u     // u32[32] stride 32: coarse-hist arrivals per rg
#define WS_HFNT    16384u     // u32[32] stride 32: fine-hist arrivals per rg
#define WS_GC      20480u     // u32 prep global counter
#define WS_SD      20608u     // u32 rg-step-done counter
#define WS_BETAS   20736u     // f32[16]
// memset 0..24576 each launch
#define WS_COARSE  24576u     // u32[4 set][4 rep][512]
#define WS_FINE    57344u     // u32[4 set][4 rep][512]
#define WS_TEP     90112u     // f32[4*8*512]
#define WS_G1P     155648u    // f32[8*8*512]
#define WS_XBF     286720u    // u16[512*64]
#define WS_XBFT0   352256u    // u16[64*512]
#define WS_XBFT1   417792u    // u16[64*512]
#define WS_INWT    483328u    // u16[512*64]
#define WS_OUTWT   548864u    // u16[64*512]
#define WS_HWT     614400u    // u16[3*512*512]
#define WS_D2      2187264u   // f32[512*512]
#define WS_H0      3235840u   // u16[512*512]
#define WS_H1      3760128u   // u16[512*512]

__device__ __forceinline__ u16 f2bf(float f) {
  u32 u = __float_as_uint(f);
  u32 r = u + 0x7FFFu + ((u >> 16) & 1u);
  return (u16)(r >> 16);
}
__device__ __forceinline__ float bf2f(u16 v) {
  return __uint_as_float(((u32)v) << 16);
}

// tanh-approx gelu (jax.nn.gelu default approximate=True)
__device__ __forceinline__ float gelu_f(float x) {
  float y = 0.7978845608028654f * (x + 0.044715f * x * x * x);
  float ay = fabsf(y);
  float e = __expf(-2.0f * ay);
  float t = (1.0f - e) / (1.0f + e);
  t = (y < 0.0f) ? -t : t;
  return 0.5f * x * (1.0f + t);
}

// ======================= sc0 sc1 (system-scope) access ======================
__device__ __forceinline__ u32 scld_u32(const u32* p) {
  u32 r;
  asm volatile("global_load_dword %0, %1, off sc0 sc1\n\ts_waitcnt vmcnt(0)"
               : "=v"(r) : "v"(p) : "memory");
  return r;
}
__device__ __forceinline__ void scld_f4(const float* p, floatx4& r) {
  asm volatile("global_load_dwordx4 %0, %1, off sc0 sc1\n\ts_waitcnt vmcnt(0)"
               : "=v"(r) : "v"(p) : "memory");
}
__device__ __forceinline__ void scld_gram(const u16* pa, const u16* pb,
                                          short8& a0, short8& a1, short8& b0, short8& b1) {
  asm volatile(
    "global_load_dwordx4 %0, %4, off sc0 sc1\n\t"
    "global_load_dwordx4 %1, %4, off offset:64 sc0 sc1\n\t"
    "global_load_dwordx4 %2, %5, off sc0 sc1\n\t"
    "global_load_dwordx4 %3, %5, off offset:64 sc0 sc1\n\t"
    "s_waitcnt vmcnt(0)"
    : "=&v"(a0), "=&v"(a1), "=&v"(b0), "=&v"(b1)
    : "v"(pa), "v"(pb) : "memory");
}
__device__ __forceinline__ void scld16_64(const u16* p, short8* a) {
  asm volatile(
    "global_load_dwordx4 %0, %16, off sc0 sc1\n\t"
    "global_load_dwordx4 %1, %16, off offset:64 sc0 sc1\n\t"
    "global_load_dwordx4 %2, %16, off offset:128 sc0 sc1\n\t"
    "global_load_dwordx4 %3, %16, off offset:192 sc0 sc1\n\t"
    "global_load_dwordx4 %4, %16, off offset:256 sc0 sc1\n\t"
    "global_load_dwordx4 %5, %16, off offset:320 sc0 sc1\n\t"
    "global_load_dwordx4 %6, %16, off offset:384 sc0 sc1\n\t"
    "global_load_dwordx4 %7, %16, off offset:448 sc0 sc1\n\t"
    "global_load_dwordx4 %8, %16, off offset:512 sc0 sc1\n\t"
    "global_load_dwordx4 %9, %16, off offset:576 sc0 sc1\n\t"
    "global_load_dwordx4 %10, %16, off offset:640 sc0 sc1\n\t"
    "global_load_dwordx4 %11, %16, off offset:704 sc0 sc1\n\t"
    "global_load_dwordx4 %12, %16, off offset:768 sc0 sc1\n\t"
    "global_load_dwordx4 %13, %16, off offset:832 sc0 sc1\n\t"
    "global_load_dwordx4 %14, %16, off offset:896 sc0 sc1\n\t"
    "global_load_dwordx4 %15, %16, off offset:960 sc0 sc1\n\t"
    "s_waitcnt vmcnt(0)"
    : "=&v"(a[0]), "=&v"(a[1]), "=&v"(a[2]), "=&v"(a[3]),
      "=&v"(a[4]), "=&v"(a[5]), "=&v"(a[6]), "=&v"(a[7]),
      "=&v"(a[8]), "=&v"(a[9]), "=&v"(a[10]), "=&v"(a[11]),
      "=&v"(a[12]), "=&v"(a[13]), "=&v"(a[14]), "=&v"(a[15])
    : "v"(p) : "memory");
}
__device__ __forceinline__ void scld4_64(const u16* p, short8& r0, short8& r1,
                                         short8& r2, short8& r3) {
  asm volatile(
    "global_load_dwordx4 %0, %4, off sc0 sc1\n\t"
    "global_load_dwordx4 %1, %4, off offset:64 sc0 sc1\n\t"
    "global_load_dwordx4 %2, %4, off offset:128 sc0 sc1\n\t"
    "global_load_dwordx4 %3, %4, off offset:192 sc0 sc1\n\t"
    "s_waitcnt vmcnt(0)"
    : "=&v"(r0), "=&v"(r1), "=&v"(r2), "=&v"(r3)
    : "v"(p) : "memory");
}
__device__ __forceinline__ void scld8_d2(const float* p, floatx4* d) {
  asm volatile(
    "global_load_dwordx4 %0, %8, off sc0 sc1\n\t"
    "global_load_dwordx4 %1, %8, off offset:16 sc0 sc1\n\t"
    "global_load_dwordx4 %2, %8, off offset:128 sc0 sc1\n\t"
    "global_load_dwordx4 %3, %8, off offset:144 sc0 sc1\n\t"
    "global_load_dwordx4 %4, %8, off offset:256 sc0 sc1\n\t"
    "global_load_dwordx4 %5, %8, off offset:272 sc0 sc1\n\t"
    "global_load_dwordx4 %6, %8, off offset:384 sc0 sc1\n\t"
    "global_load_dwordx4 %7, %8, off offset:400 sc0 sc1\n\t"
    "s_waitcnt vmcnt(0)"
    : "=&v"(d[0]), "=&v"(d[1]), "=&v"(d[2]), "=&v"(d[3]),
      "=&v"(d[4]), "=&v"(d[5]), "=&v"(d[6]), "=&v"(d[7])
    : "v"(p) : "memory");
}
__device__ __forceinline__ void scld4_u2(const u32* p0, const u32* p1,
                                         const u32* p2, const u32* p3,
                                         u32x2& r0, u32x2& r1, u32x2& r2, u32x2& r3) {
  asm volatile(
    "global_load_dwordx2 %0, %4, off sc0 sc1\n\t"
    "global_load_dwordx2 %1, %5, off sc0 sc1\n\t"
    "global_load_dwordx2 %2, %6, off sc0 sc1\n\t"
    "global_load_dwordx2 %3, %7, off sc0 sc1\n\t"
    "s_waitcnt vmcnt(0)"
    : "=&v"(r0), "=&v"(r1), "=&v"(r2), "=&v"(r3)
    : "v"(p0), "v"(p1), "v"(p2), "v"(p3) : "memory");
}
__device__ __forceinline__ void scst_f32(float* p, float v) {
  asm volatile("global_store_dword %0, %1, off sc0 sc1" :: "v"(p), "v"(v) : "memory");
}
__device__ __forceinline__ void scst_u32(u32* p, u32 v) {
  asm volatile("global_store_dword %0, %1, off sc0 sc1" :: "v"(p), "v"(v) : "memory");
}
__device__ __forceinline__ void scst_u16(u16* p, u16 v) {
  u32 x = v;
  asm volatile("global_store_short %0, %1, off sc0 sc1" :: "v"(p), "v"(x) : "memory");
}

#define MFMA(a, b, c) __builtin_amdgcn_mfma_f32_16x16x32_bf16((a), (b), (c), 0, 0, 0)

__global__ __launch_bounds__(256) void mega(
    const float* __restrict__ particles, const float* __restrict__ noises,
    const float* __restrict__ grid_t, const float* __restrict__ eps,
    const float* __restrict__ mu, const float* __restrict__ phase,
    const float* __restrict__ in_W, const float* __restrict__ in_b,
    const float* __restrict__ t_W1, const float* __restrict__ t_b1,
    const float* __restrict__ t_W2, const float* __restrict__ t_b2,
    const float* __restrict__ h_W, const float* __restrict__ h_b,
    const float* __restrict__ out_W, const float* __restrict__ out_b,
    float* __restrict__ traj, char* __restrict__ ws)
{
  __shared__ u32 su[512];
  __shared__ float sf[3200];
  __shared__ float medf[4];
  __shared__ float rn_s[16];

  u32* rgcnt = (u32*)(ws + WS_RGCNT);
  u32* rgdone = (u32*)(ws + WS_RGDONE);
  u32* rgrel = (u32*)(ws + WS_RGREL);
  u32* hcnt = (u32*)(ws + WS_HCNT);
  u32* hfnt = (u32*)(ws + WS_HFNT);
  u32* GC = (u32*)(ws + WS_GC);
  u32* SD = (u32*)(ws + WS_SD);
  float* BET = (float*)(ws + WS_BETAS);
  u32* coarse = (u32*)(ws + WS_COARSE);
  u32* fine = (u32*)(ws + WS_FINE);
  float* TEP = (float*)(ws + WS_TEP);
  float* G1P = (float*)(ws + WS_G1P);
  u16* xbf = (u16*)(ws + WS_XBF);
  u16* inWT = (u16*)(ws + WS_INWT);
  u16* outWT = (u16*)(ws + WS_OUTWT);
  u16* hWT = (u16*)(ws + WS_HWT);
  float* d2g = (float*)(ws + WS_D2);
  u16* h0g = (u16*)(ws + WS_H0);
  u16* h1g = (u16*)(ws + WS_H1);

  const int b = blockIdx.x;
  const int tid = threadIdx.x;
  const int wv = tid >> 6, lane = tid & 63;
  const int m = lane & 15, q = lane >> 4;
  const int rg = b >> 3, cg = b & 7;
  u32 lrnd = 0, grnd = 0;

  // local sync macro pattern (extra = additional per-rg arrival counter or null)
#define LSYNC(extra_ptr)                                                        \
  do {                                                                          \
    lrnd++;                                                                     \
    asm volatile("s_waitcnt vmcnt(0)" ::: "memory");                            \
    __syncthreads();                                                            \
    if (tid == 0) {                                                             \
      u32* _e = (extra_ptr);                                                    \
      if (_e) __hip_atomic_fetch_add(_e, 1u, __ATOMIC_RELAXED, __HIP_MEMORY_SCOPE_AGENT); \
      __hip_atomic_fetch_add(&rgcnt[rg * 32], 1u, __ATOMIC_RELAXED, __HIP_MEMORY_SCOPE_AGENT); \
      while (scld_u32(&rgcnt[rg * 32]) < 8u * lrnd) __builtin_amdgcn_s_sleep(1); \
    }                                                                           \
    __syncthreads();                                                            \
  } while (0)

#define GBAR_HEAVY()                                                            \
  do {                                                                          \
    lrnd++; grnd++;                                                             \
    asm volatile("s_waitcnt vmcnt(0)" ::: "memory");                            \
    __syncthreads();                                                            \
    if (tid == 0) {                                                             \
      __threadfence();                                                          \
      __hip_atomic_fetch_add(&rgcnt[rg * 32], 1u, __ATOMIC_RELAXED, __HIP_MEMORY_SCOPE_AGENT); \
      if (cg == 0) {                                                            \
        while (scld_u32(&rgcnt[rg * 32]) < 8u * lrnd) __builtin_amdgcn_s_sleep(2); \
        __hip_atomic_fetch_add(GC, 1u, __ATOMIC_RELAXED, __HIP_MEMORY_SCOPE_AGENT); \
        while (scld_u32(GC) < 32u * grnd) __builtin_amdgcn_s_sleep(2);          \
        scst_u32(&rgrel[rg * 32], grnd);                                        \
      } else {                                                                  \
        while (scld_u32(&rgrel[rg * 32]) < grnd) __builtin_amdgcn_s_sleep(2);   \
      }                                                                         \
      __threadfence();                                                          \
    }                                                                           \
    __syncthreads();                                                            \
  } while (0)

  // ================= P0: prep jobs (plain stores; heavy-synced) =============
  for (int j = b; j < 916; j += 256) {
    if (j < 64) {                      // t-MLP pre-act partial, K-chain 128
      int slice = j >> 3, ii = j & 7;
      float* temb = sf;
      if (tid < 128) {
        int kglob = slice * 128 + tid;
        int kc = kglob & 511;
        float cf = 0.1f + (float)kc * (99.9f / 511.0f);
        float e = cf * (float)ii + phase[kc];
        temb[tid] = (kglob < 512) ? sinf(e) : cosf(e);
      }
      __syncthreads();
      for (int h = 0; h < 2; h++) {
        int c = h * 256 + tid;
        float acc = (slice == 0) ? t_b1[c] : 0.0f;
        const float* wp = t_W1 + (u32)(slice * 128) * 512u + c;
#pragma unroll 8
        for (int kk = 0; kk < 128; kk++) acc = fmaf(temb[kk], wp[kk * 512], acc);
        G1P[(slice * 8 + ii) * 512 + c] = acc;
      }
    } else if (j < 896) {              // LDS-tiled weight transposes -> bf16
      float* tile = sf;                // [32][33]
      int tx = tid & 31, ty0 = tid >> 5;
      const float* src; u16* dst; int sstr, dstr;
      if (j < 832) {
        int ti = j - 64; int l = ti >> 8, rem = ti & 255, kt = rem >> 4, ct = rem & 15;
        src = h_W + l * 262144 + kt * 32 * 512 + ct * 32; sstr = 512;
        dst = hWT + l * 262144 + ct * 32 * 512 + kt * 32; dstr = 512;
      } else if (j < 864) {
        int ti = j - 832; int kt = ti >> 4, ct = ti & 15;
        src = in_W + kt * 32 * 512 + ct * 32; sstr = 512;
        dst = inWT + ct * 32 * 64 + kt * 32; dstr = 64;
      } else {
        int ti = j - 864; int ct = ti >> 4, kt = ti & 15;
        src = out_W + kt * 32 * 64 + ct * 32; sstr = 64;
        dst = outWT + ct * 32 * 512 + kt * 32; dstr = 512;
      }
#pragma unroll
      for (int r = 0; r < 4; r++) { int ty = ty0 + r * 8; tile[ty * 33 + tx] = src[ty * sstr + tx]; }
      __syncthreads();
#pragma unroll
      for (int r = 0; r < 4; r++) { int ty = ty0 + r * 8; dst[ty * dstr + tx] = f2bf(tile[tx * 33 + ty]); }
    } else if (j < 912) {              // x copies: traj row0, xbf, xbfT0
      int jj = j - 896;
      u16* xbfT0 = (u16*)(ws + WS_XBFT0);
#pragma unroll
      for (int k2 = 0; k2 < 8; k2++) {
        u32 e = (u32)jj * 2048u + (u32)(k2 * 256) + (u32)tid;
        float v = particles[e];
        traj[e] = v;
        u16 bv = f2bf(v);
        xbf[e] = bv;
        xbfT0[(e & 63u) * 512u + (e >> 6)] = bv;
      }
    } else {                           // hist zero (all 4 sets) + betas
      u32 base = (u32)(j - 912) * 4096u;
      for (int k2 = 0; k2 < 16; k2++) {
        u32 w = base + (u32)(k2 * 256) + (u32)tid;
        if (w < 8192u) coarse[w] = 0u; else fine[w - 8192u] = 0u;
      }
      if (j == 912 && tid == 0) {
        float sig[8]; float tot = 0.f;
        for (int k2 = 0; k2 < 8; k2++) { sig[k2] = 1.0f / (1.0f + __expf(-grid_t[k2])); tot += sig[k2]; }
        float cum = 0.f; BET[0] = 0.f;
        for (int k2 = 0; k2 < 8; k2++) { cum += sig[k2]; BET[k2 + 1] = cum / tot; }
      }
    }
    __syncthreads();
  }
  GBAR_HEAVY();

  // ================= P0b: te partial slabs (32 jobs) =========================
  if (b < 32) {
    int ii = b >> 2, kq = b & 3;
    float* g1 = sf;
    if (tid < 128) {
      int kglob = kq * 128 + tid;
      float s = 0.f;
#pragma unroll
      for (int sl = 0; sl < 8; sl++) s += G1P[(sl * 8 + ii) * 512 + kglob];
      g1[tid] = gelu_f(s);
    }
    __syncthreads();
    for (int h = 0; h < 2; h++) {
      int c = h * 256 + tid;
      float acc = (kq == 0) ? (t_b2[c] + in_b[c]) : 0.0f;
      const float* wp = t_W2 + (u32)(kq * 128) * 512u + c;
#pragma unroll 8
      for (int kk = 0; kk < 128; kk++) acc = fmaf(g1[kk], wp[kk * 512], acc);
      TEP[(kq * 8 + ii) * 512 + c] = acc;
    }
  }
  GBAR_HEAVY();   // after this, weights/TEP/BET are immutable & cacheable

  // ================= main loop ==============================================
  const int r0 = rg * 16;
  const int cA = cg * 64;

  for (int step = 0; step < 8; step++) {
    const int hs = step & 3;
    u32* corP = coarse + hs * 2048;
    u32* finP = fine + hs * 2048;
    const u16* xT_in = (const u16*)(ws + ((step & 1) ? WS_XBFT1 : WS_XBFT0));
    u16* xT_out = (u16*)(ws + ((step & 1) ? WS_XBFT0 : WS_XBFT1));
    const float* x_old = traj + step * 32768;
    float* x_new = traj + (step + 1) * 32768;
    const float* noise_i = noises + step * 32768;

    // -------- P1: flag-wait, gram + coarse hist + L0 ------------------------
    if (tid < 5) {
      int need = (tid < 4) ? (4 * cg + tid) : rg;
      while (scld_u32(&rgdone[need * 32]) < (u32)step) __builtin_amdgcn_s_sleep(1);
    }
    __syncthreads();
    floatx4 d2r;
    {
      int c0 = cA + wv * 16;
      short8 a0, a1, b0, b1;
      scld_gram(xbf + (r0 + m) * 64 + q * 8, xbf + (c0 + m) * 64 + q * 8, a0, a1, b0, b1);
      float rp = 0.f, cp = 0.f;
#pragma unroll
      for (int jj = 0; jj < 8; jj++) {
        float v;
        v = bf2f((u16)a0[jj]); rp = fmaf(v, v, rp);
        v = bf2f((u16)a1[jj]); rp = fmaf(v, v, rp);
        v = bf2f((u16)b0[jj]); cp = fmaf(v, v, cp);
        v = bf2f((u16)b1[jj]); cp = fmaf(v, v, cp);
      }
      rp += __shfl_xor(rp, 16); rp += __shfl_xor(rp, 32);
      cp += __shfl_xor(cp, 16); cp += __shfl_xor(cp, 32);
      if (wv == 0 && q == 0) rn_s[m] = rp;
      su[tid] = 0u; su[256 + tid] = 0u;
      __syncthreads();
      floatx4 acc = {0.f, 0.f, 0.f, 0.f};
      acc = MFMA(a0, b0, acc);
      acc = MFMA(a1, b1, acc);
#pragma unroll
      for (int rg2 = 0; rg2 < 4; rg2++) {
        int rl = q * 4 + rg2;
        float v = rn_s[rl] + cp - 2.0f * acc[rg2];
        d2r[rg2] = v;
        scst_f32(d2g + (r0 + rl) * 512 + c0 + m, v);
        int bin = (int)(v * 0.5f);
        bin = bin < 0 ? 0 : (bin > 511 ? 511 : bin);
        atomicAdd(&su[bin], 1u);
      }
      __syncthreads();
      u32 rep = (u32)(b & 3) * 512u;
      u32 v0 = su[tid]; if (v0) atomicAdd(&corP[rep + tid], v0);
      u32 v1 = su[256 + tid]; if (v1) atomicAdd(&corP[rep + 256 + tid], v1);
      // L0
      short8 w0 = *(const short8*)(inWT + (c0 + m) * 64 + q * 8);
      short8 w1 = *(const short8*)(inWT + (c0 + m) * 64 + 32 + q * 8);
      floatx4 fac = {0.f, 0.f, 0.f, 0.f};
      fac = MFMA(a0, w0, fac);
      fac = MFMA(a1, w1, fac);
      int col = c0 + m;
      float bv = TEP[step * 512 + col] + TEP[4096 + step * 512 + col]
               + TEP[8192 + step * 512 + col] + TEP[12288 + step * 512 + col];
#pragma unroll
      for (int rg2 = 0; rg2 < 4; rg2++)
        scst_u16(h0g + (r0 + q * 4 + rg2) * 512 + col, f2bf(gelu_f(fac[rg2] + bv)));
    }
    LSYNC(&hcnt[rg * 32]);

    // -------- P2: L1 --------------------------------------------------------
    {
      int c0 = cA + wv * 16;
      short8 a[16];
      scld16_64(h0g + (r0 + m) * 512 + q * 8, a);
      floatx4 acc = {0.f, 0.f, 0.f, 0.f};
#pragma unroll
      for (int kk = 0; kk < 16; kk++) {
        short8 bb = *(const short8*)(hWT + (c0 + m) * 512 + kk * 32 + q * 8);
        acc = MFMA(a[kk], bb, acc);
      }
      int col = c0 + m;
      float bv = h_b[col];
#pragma unroll
      for (int rg2 = 0; rg2 < 4; rg2++)
        scst_u16(h1g + (r0 + q * 4 + rg2) * 512 + col, f2bf(gelu_f(acc[rg2] + bv)));
    }
    LSYNC((u32*)0);

    // -------- P3: L2 + coarse scan + fine contrib ---------------------------
    u32 base0; float lo2, invbw, binw;
    {
      int c0 = cA + wv * 16;
      short8 a[16];
      scld16_64(h1g + (r0 + m) * 512 + q * 8, a);
      floatx4 acc = {0.f, 0.f, 0.f, 0.f};
#pragma unroll
      for (int kk = 0; kk < 16; kk++) {
        short8 bb = *(const short8*)(hWT + 262144 + (c0 + m) * 512 + kk * 32 + q * 8);
        acc = MFMA(a[kk], bb, acc);
      }
      int col = c0 + m;
      float bv = h_b[512 + col];
#pragma unroll
      for (int rg2 = 0; rg2 < 4; rg2++)
        scst_u16(h0g + (r0 + q * 4 + rg2) * 512 + col, f2bf(gelu_f(acc[rg2] + bv)));

      // wait: all coarse-hist arrivals (per-rg lines; hidden by 2-phase lag)
      if (tid < 32) {
        while (scld_u32(&hcnt[tid * 32]) < 8u * (u32)(step + 1)) __builtin_amdgcn_s_sleep(1);
      }
      __syncthreads();
      // coarse scan (pairs: thread t handles bins 2t, 2t+1)
      u32x2 h0p, h1p, h2p, h3p;
      scld4_u2(&corP[2 * tid], &corP[512 + 2 * tid], &corP[1024 + 2 * tid], &corP[1536 + 2 * tid],
               h0p, h1p, h2p, h3p);
      u32 c0c = h0p.x + h1p.x + h2p.x + h3p.x;
      u32 c1c = h0p.y + h1p.y + h2p.y + h3p.y;
      su[tid] = c0c + c1c;
      __syncthreads();
      for (int off = 1; off < 256; off <<= 1) {
        u32 add = (tid >= off) ? su[tid - off] : 0u;
        __syncthreads(); su[tid] += add; __syncthreads();
      }
      u32 incl = su[tid], excl = incl - c0c - c1c;
#pragma unroll
      for (int tr = 0; tr < 2; tr++) {
        u32 R = 131071u + (u32)tr;
        if (R >= excl && R < excl + c0c) { su[300 + tr] = 2u * tid; if (tr == 0) su[304] = excl; }
        else if (R >= excl + c0c && R < incl) { su[300 + tr] = 2u * tid + 1u; if (tr == 0) su[304] = excl + c0c; }
      }
      __syncthreads();
      u32 cb0 = su[300], cb1 = su[301];
      base0 = su[304];
      lo2 = (float)cb0 * 2.0f;
      float width = (float)(cb1 - cb0 + 1u) * 2.0f;
      invbw = 512.0f / width;
      binw = width * (1.0f / 512.0f);
      __syncthreads();
      su[tid] = 0u; su[256 + tid] = 0u;
      __syncthreads();
#pragma unroll
      for (int rg2 = 0; rg2 < 4; rg2++) {
        float v = d2r[rg2];
        int cbv = (int)(v * 0.5f); cbv = cbv < 0 ? 0 : (cbv > 511 ? 511 : cbv);
        if ((u32)cbv >= cb0 && (u32)cbv <= cb1) {
          int fb = (int)((v - lo2) * invbw);
          fb = fb < 0 ? 0 : (fb > 511 ? 511 : fb);
          atomicAdd(&su[fb], 1u);
        }
      }
      __syncthreads();
      u32 rep = (u32)(b & 3) * 512u;
      u32 v0 = su[tid]; if (v0) atomicAdd(&finP[rep + tid], v0);
      u32 v1 = su[256 + tid]; if (v1) atomicAdd(&finP[rep + 256 + tid], v1);
    }
    LSYNC(&hfnt[rg * 32]);

    // -------- P4: L3 --------------------------------------------------------
    {
      int c0 = cA + wv * 16;
      short8 a[16];
      scld16_64(h0g + (r0 + m) * 512 + q * 8, a);
      floatx4 acc = {0.f, 0.f, 0.f, 0.f};
#pragma unroll
      for (int kk = 0; kk < 16; kk++) {
        short8 bb = *(const short8*)(hWT + 524288 + (c0 + m) * 512 + kk * 32 + q * 8);
        acc = MFMA(a[kk], bb, acc);
      }
      int col = c0 + m;
      float bv = h_b[1024 + col];
#pragma unroll
      for (int rg2 = 0; rg2 < 4; rg2++)
        scst_u16(h1g + (r0 + q * 4 + rg2) * 512 + col, f2bf(gelu_f(acc[rg2] + bv)));
    }
    LSYNC((u32*)0);

    // -------- P5: update (cg<4... b<128) / hist-zero (b>=128) ---------------
    // merged poll: lanes 0..31 -> hfnt[all rgs]; lane 32 -> SD
    if (tid < 33) {
      const u32* ap = (tid < 32) ? &hfnt[tid * 32] : SD;
      u32 tgt = (tid < 32) ? 8u * (u32)(step + 1) : 32u * (u32)step;
      while (scld_u32(ap) < tgt) __builtin_amdgcn_s_sleep(1);
    }
    __syncthreads();
    if (b < 128) {
      const int urg = b >> 2, uct = b & 3;
      const int ur0 = urg * 16, uc0 = uct * 16;
      // stage x_old rows into LDS
      float* xold = sf + 2112;   // [16][64]
      {
        int r = tid >> 4, c4 = tid & 15;
        floatx4 xv4;
        scld_f4(x_old + (ur0 + r) * 64 + c4 * 4, xv4);
        *(floatx4*)(xold + r * 64 + c4 * 4) = xv4;
      }
      // fine median select
      {
        u32x2 f0p, f1p, f2p, f3p;
        scld4_u2(&finP[2 * tid], &finP[512 + 2 * tid], &finP[1024 + 2 * tid], &finP[1536 + 2 * tid],
                 f0p, f1p, f2p, f3p);
        u32 f0 = f0p.x + f1p.x + f2p.x + f3p.x;
        u32 f1 = f0p.y + f1p.y + f2p.y + f3p.y;
        su[tid] = f0 + f1;
        __syncthreads();
        for (int off = 1; off < 256; off <<= 1) {
          u32 add = (tid >= off) ? su[tid - off] : 0u;
          __syncthreads(); su[tid] += add; __syncthreads();
        }
        u32 incl = su[tid], excl = incl - f0 - f1;
#pragma unroll
        for (int tr = 0; tr < 2; tr++) {
          u32 rl = 131071u + (u32)tr - base0;
          u32 fb = 0, flo = 0, cnt = 0; bool hit = false;
          if (rl >= excl && rl < excl + f0) { fb = 2u * tid; flo = excl; cnt = f0; hit = true; }
          else if (rl >= excl + f0 && rl < incl) { fb = 2u * tid + 1u; flo = excl + f0; cnt = f1; hit = true; }
          if (hit) {
            float d2v = lo2 + ((float)fb + ((float)(rl - flo) + 0.5f) / (float)cnt) * binw;
            medf[tr] = sqrtf(fmaxf(d2v, 1e-12f));
          }
        }
        __syncthreads();
        if (tid == 0) {
          float md = 0.5f * (medf[0] + medf[1]);
          medf[2] = 6.2383246250395075f / (md * md);   // log(512)/h_t
        }
        __syncthreads();
      }
      float inv_ht = medf[2];
      // score + S1 GEMMs, wave wv = K-slice of 4 kk
      short8 ha0, ha1, ha2, ha3, xb0, xb1, xb2, xb3;
      scld4_64(h1g + (ur0 + m) * 512 + wv * 128 + q * 8, ha0, ha1, ha2, ha3);
      scld4_64(xT_in + (uc0 + m) * 512 + wv * 128 + q * 8, xb0, xb1, xb2, xb3);
      floatx4 dv[8];
      scld8_d2(d2g + (ur0 + m) * 512 + wv * 128 + q * 8, dv);
      floatx4 accS = {0.f, 0.f, 0.f, 0.f}, accR = {0.f, 0.f, 0.f, 0.f};
      float s0 = 0.f;
      short8 has[4] = {ha0, ha1, ha2, ha3};
      short8 xbs[4] = {xb0, xb1, xb2, xb3};
#pragma unroll
      for (int kl = 0; kl < 4; kl++) {
        int kk = wv * 4 + kl;
        short8 bw = *(const short8*)(outWT + (uc0 + m) * 512 + kk * 32 + q * 8);
        accS = MFMA(has[kl], bw, accS);
        short8 wf;
#pragma unroll
        for (int jj = 0; jj < 8; jj++) {
          float w = __expf(-dv[2 * kl + (jj >> 2)][jj & 3] * inv_ht);
          s0 += w;
          wf[jj] = (short)f2bf(w);
        }
        accR = MFMA(wf, xbs[kl], accR);
      }
      s0 += __shfl_xor(s0, 16);
      s0 += __shfl_xor(s0, 32);
      float* combS = sf;           // [3][64][4]
      float* combR = sf + 768;
      float* sc_s = sf + 1536;     // [16][16]
      float* s1_s = sf + 1792;
      float* s0p  = sf + 2048;     // [16][4]
      if (wv) {
#pragma unroll
        for (int rg2 = 0; rg2 < 4; rg2++) {
          combS[((wv - 1) * 64 + lane) * 4 + rg2] = accS[rg2];
          combR[((wv - 1) * 64 + lane) * 4 + rg2] = accR[rg2];
        }
      }
      if (q == 0) s0p[m * 4 + wv] = s0;
      __syncthreads();
      if (wv == 0) {
        float ob = out_b[uc0 + m];
#pragma unroll
        for (int rg2 = 0; rg2 < 4; rg2++) {
          float aS = accS[rg2], aR = accR[rg2];
#pragma unroll
          for (int w2 = 0; w2 < 3; w2++) {
            aS += combS[(w2 * 64 + lane) * 4 + rg2];
            aR += combR[(w2 * 64 + lane) * 4 + rg2];
          }
          sc_s[(q * 4 + rg2) * 16 + m] = aS + ob;
          s1_s[(q * 4 + rg2) * 16 + m] = aR;
        }
      }
      __syncthreads();
      float* comp = sf;        // [16][8] (combS dead)
      float* w8   = sf + 128;  // [16][8]
      float* wm   = sf + 256;  // [16][16]
      if (tid < 128) {
        int r = tid >> 3, mm = tid & 7;
        const float* xr = xold + r * 64;
        const float* mr = mu + mm * 64;
        float s = 0.f;
#pragma unroll 8
        for (int d = 0; d < 64; d++) { float df = xr[d] - mr[d]; s = fmaf(df, df, s); }
        comp[r * 8 + mm] = -0.5f * s;
      }
      __syncthreads();
      if (tid < 16) {
        float mx = comp[tid * 8];
        for (int j2 = 1; j2 < 8; j2++) mx = fmaxf(mx, comp[tid * 8 + j2]);
        float sm = 0.f; float e[8];
        for (int j2 = 0; j2 < 8; j2++) { e[j2] = __expf(comp[tid * 8 + j2] - mx); sm += e[j2]; }
        float inv = 1.0f / sm;
        for (int j2 = 0; j2 < 8; j2++) w8[tid * 8 + j2] = e[j2] * inv;
      }
      __syncthreads();
      {
        int r = tid >> 4, dl = tid & 15;
        float a2 = 0.f;
#pragma unroll
        for (int mm = 0; mm < 8; mm++) a2 = fmaf(w8[r * 8 + mm], mu[mm * 64 + uc0 + dl], a2);
        wm[r * 16 + dl] = a2;
      }
      __syncthreads();
      {
        float tb = BET[step];
        float dt = eps[0];
        float sq = sqrtf(2.0f * dt);
        int r = tid >> 4, dl = tid & 15;
        int grow = ur0 + r, d = uc0 + dl;
        float s0r = s0p[r * 4] + s0p[r * 4 + 1] + s0p[r * 4 + 2] + s0p[r * 4 + 3];
        float cR = -0.1f * inv_ht;
        float xv = xold[r * 64 + d];
        float g = -xv + tb * wm[r * 16 + dl];                // grad log pi
        float rep = cR * (xv * s0r - s1_s[r * 16 + dl]);     // repel(x_old)
        float nv = xv + dt * (g - sc_s[r * 16 + dl]) - dt * rep + sq * noise_i[grow * 64 + d];
        scst_f32(x_new + grow * 64 + d, nv);
        u16 bv = f2bf(nv);
        scst_u16(xbf + grow * 64 + d, bv);
        scst_u16(xT_out + d * 512 + grow, bv);
      }
    } else {
      // zero hist set (step+2)%4 for reuse at step+2
      int zs = (step + 2) & 3;
      u32* zc = coarse + zs * 2048;
      u32* zf = fine + zs * 2048;
      int bb = b - 128;   // 0..127
      if (tid < 16) {
        int w = bb * 16 + tid;
        scst_u32(&zc[w], 0u);
        scst_u32(&zf[w], 0u);
      }
    }
    LSYNC((u32*)0);
    if (tid == 0 && cg == 0) {
      __hip_atomic_fetch_add(SD, 1u, __ATOMIC_RELAXED, __HIP_MEMORY_SCOPE_AGENT);
      scst_u32(&rgdone[rg * 32], (u32)(step + 1));
    }
  }
#undef LSYNC
#undef GBAR_HEAVY
}

extern "C" void kernel_launch(void* const* d_in, const int* in_sizes, int n_in,
                              void* d_out, int out_size, void* d_ws, size_t ws_size,
                              hipStream_t stream) {
  (void)in_sizes; (void)n_in; (void)out_size; (void)ws_size;
  const float* particles    = (const float*)d_in[0];
  const float* noises       = (const float*)d_in[1];
  const float* grid_t       = (const float*)d_in[2];
  const float* eps          = (const float*)d_in[3];
  const float* target_means = (const float*)d_in[4];
  const float* phase        = (const float*)d_in[5];
  const float* in_W         = (const float*)d_in[6];
  const float* in_b         = (const float*)d_in[7];
  const float* t_W1         = (const float*)d_in[8];
  const float* t_b1         = (const float*)d_in[9];
  const float* t_W2         = (const float*)d_in[10];
  const float* t_b2         = (const float*)d_in[11];
  const float* h_W          = (const float*)d_in[12];
  const float* h_b          = (const float*)d_in[13];
  const float* out_W        = (const float*)d_in[14];
  const float* out_b        = (const float*)d_in[15];
  float* traj = (float*)d_out;
  char* ws = (char*)d_ws;

  hipMemsetAsync(ws, 0, 24576, stream);   // counters / flags / release words

  void* args[] = {
    (void*)&particles, (void*)&noises, (void*)&grid_t, (void*)&eps,
    (void*)&target_means, (void*)&phase, (void*)&in_W, (void*)&in_b,
    (void*)&t_W1, (void*)&t_b1, (void*)&t_W2, (void*)&t_b2,
    (void*)&h_W, (void*)&h_b, (void*)&out_W, (void*)&out_b,
    (void*)&traj, (void*)&ws
  };
  hipLaunchCooperativeKernel((void*)mega, dim3(256), dim3(256), args, 0, stream);
}